// Round 8
// baseline (282.467 us; speedup 1.0000x reference)
//
#include <hip/hip_runtime.h>
#include <stdint.h>

typedef unsigned short u16;
typedef __bf16 bf16x8 __attribute__((ext_vector_type(8)));
typedef float f32x4 __attribute__((ext_vector_type(4)));

#define D_MODEL 1024
#define NHEADS  16
#define DHEAD   64
#define BATCH   8
#define SEQ     1024
#define MTOT    (BATCH*SEQ)          // 8192 rows

#define GPTR(p) ((const __attribute__((address_space(1))) void*)(p))
#define LPTR(p) ((__attribute__((address_space(3))) void*)(p))

__device__ __forceinline__ u16 f2bf(float f) {
    union { float f; uint32_t u; } v; v.f = f;
    uint32_t u = v.u;
    u += 0x7fffu + ((u >> 16) & 1u);  // RNE
    return (u16)(u >> 16);
}

// pack low16 of two ints: result = [i1.low16 : i0.low16] (i0 in low half)
__device__ __forceinline__ uint32_t pklo(int i1, int i0) {
    return __builtin_amdgcn_perm((uint32_t)i1, (uint32_t)i0, 0x05040100u);
}

// ---------------------------------------------------------------- LayerNorm
__global__ __launch_bounds__(256) void ln_kernel(
    const float* __restrict__ z, const float* __restrict__ w,
    const float* __restrict__ b, u16* __restrict__ zn)
{
    const int row = blockIdx.x;
    const int t = threadIdx.x;
    const float4 v = reinterpret_cast<const float4*>(z + (size_t)row * D_MODEL)[t];
    float s  = v.x + v.y + v.z + v.w;
    float s2 = v.x*v.x + v.y*v.y + v.z*v.z + v.w*v.w;
    #pragma unroll
    for (int off = 32; off; off >>= 1) {
        s  += __shfl_down(s,  off, 64);
        s2 += __shfl_down(s2, off, 64);
    }
    __shared__ float red[8];
    const int wave = t >> 6, lane = t & 63;
    if (lane == 0) { red[wave] = s; red[wave + 4] = s2; }
    __syncthreads();
    if (t == 0) {
        float ts  = red[0] + red[1] + red[2] + red[3];
        float ts2 = red[4] + red[5] + red[6] + red[7];
        float mu  = ts * (1.0f / D_MODEL);
        float var = ts2 * (1.0f / D_MODEL) - mu * mu;
        red[0] = mu; red[1] = rsqrtf(var + 1e-5f);
    }
    __syncthreads();
    const float mu = red[0], rstd = red[1];
    const float4 wv = reinterpret_cast<const float4*>(w)[t];
    const float4 bv = reinterpret_cast<const float4*>(b)[t];
    ushort4 o;
    o.x = f2bf((v.x - mu) * rstd * wv.x + bv.x);
    o.y = f2bf((v.y - mu) * rstd * wv.y + bv.y);
    o.z = f2bf((v.z - mu) * rstd * wv.z + bv.z);
    o.w = f2bf((v.w - mu) * rstd * wv.w + bv.w);
    reinterpret_cast<ushort4*>(zn + (size_t)row * D_MODEL)[t] = o;
}

// ----------------------------------------------- weight transpose + bf16 cast
__global__ __launch_bounds__(256) void transpose_cast(
    const float* __restrict__ in, u16* __restrict__ out, int R, int C)
{
    __shared__ u16 tile[32][33];
    const int c0 = blockIdx.x * 32, r0 = blockIdx.y * 32;
    const int tx = threadIdx.x & 31, ty = threadIdx.x >> 5;   // 32x8
    #pragma unroll
    for (int i = 0; i < 4; ++i)
        tile[ty + i*8][tx] = f2bf(in[(size_t)(r0 + ty + i*8) * C + c0 + tx]);
    __syncthreads();
    #pragma unroll
    for (int i = 0; i < 4; ++i)
        out[(size_t)(c0 + ty + i*8) * R + r0 + tx] = tile[tx][ty + i*8];
}

// -------------------------------------------------- V transpose: [b,h,t,dh] -> [b,h,dh,t]
__global__ __launch_bounds__(256) void transpose_v(
    const u16* __restrict__ in, u16* __restrict__ out)
{
    __shared__ u16 tile[64][65];
    const int bh = blockIdx.y;          // 0..127
    const int t0 = blockIdx.x * 64;     // 16 t-tiles
    const int tid = threadIdx.x;
    const u16* src = in + ((size_t)bh * SEQ + t0) * DHEAD;
    #pragma unroll
    for (int i = 0; i < 4; ++i) {
        const int row = (tid >> 4) + i * 16;       // t within tile
        const int c4  = (tid & 15) * 4;            // dh chunk
        *reinterpret_cast<ushort4*>(&tile[row][c4]) =
            *reinterpret_cast<const ushort4*>(&src[(size_t)row * DHEAD + c4]);
    }
    __syncthreads();
    u16* dst = out + (size_t)bh * DHEAD * SEQ + t0;
    #pragma unroll
    for (int i = 0; i < 4; ++i) {
        const int dh = (tid >> 4) + i * 16;
        const int tt = (tid & 15) * 4;
        ushort4 o;
        o.x = tile[tt+0][dh]; o.y = tile[tt+1][dh];
        o.z = tile[tt+2][dh]; o.w = tile[tt+3][dh];
        *reinterpret_cast<ushort4*>(&dst[(size_t)dh * SEQ + tt]) = o;
    }
}

// ---------------------------------------------------------------- GEMM core
// A [M][1024] bf16 row-major, Bt [N][1024] bf16, 128x128 tile, BK=64, 4 waves.
// global_load_lds width-16 staging; XOR swizzle (seg^(row&7)) -> conflict-free.
// MFMA operands SWAPPED (bfr first): acc[i][j][r] = C[m...lm][n...4g+r].
#define GEMM_MAINLOOP(A_, Bt_)                                                  \
    __shared__ u16 As[128 * 64];                                                \
    __shared__ u16 Bs[128 * 64];                                                \
    const int tid = threadIdx.x;                                                \
    const int wave = tid >> 6, lane = tid & 63;                                 \
    const int lm = lane & 15, g = lane >> 4;                                    \
    const int wm = (wave >> 1) * 64, wn = (wave & 1) * 64;                      \
    const int m0 = blockIdx.y * 128, n0 = blockIdx.x * 128;                     \
    const int srow = tid >> 3;                 /* 0..31 */                      \
    const int sseg = tid & 7;                                                   \
    const int sgcol = (sseg ^ (srow & 7)) * 8; /* swizzled global chunk */      \
    const int xl = lm & 7;                                                      \
    f32x4 acc[4][4] = {};                                                       \
    for (int k0 = 0; k0 < D_MODEL; k0 += 64) {                                  \
        _Pragma("unroll")                                                       \
        for (int c = 0; c < 4; ++c) {                                           \
            const int r = srow + c * 32;                                        \
            __builtin_amdgcn_global_load_lds(                                   \
                GPTR(&A_[(size_t)(m0 + r) * D_MODEL + k0 + sgcol]),             \
                LPTR(&As[r * 64 + sseg * 8]), 16, 0, 0);                        \
            __builtin_amdgcn_global_load_lds(                                   \
                GPTR(&Bt_[(size_t)(n0 + r) * D_MODEL + k0 + sgcol]),            \
                LPTR(&Bs[r * 64 + sseg * 8]), 16, 0, 0);                        \
        }                                                                       \
        __syncthreads();                                                        \
        _Pragma("unroll")                                                       \
        for (int ko = 0; ko < 2; ++ko) {                                        \
            const int ca = ((ko * 4 + g) ^ xl) * 8;                             \
            bf16x8 af[4], bfr[4];                                               \
            _Pragma("unroll")                                                   \
            for (int i = 0; i < 4; ++i) {                                       \
                af[i]  = *reinterpret_cast<const bf16x8*>(                      \
                    &As[(wm + i*16 + lm) * 64 + ca]);                           \
                bfr[i] = *reinterpret_cast<const bf16x8*>(                      \
                    &Bs[(wn + i*16 + lm) * 64 + ca]);                           \
            }                                                                   \
            _Pragma("unroll")                                                   \
            for (int i = 0; i < 4; ++i)                                         \
                _Pragma("unroll")                                               \
                for (int j = 0; j < 4; ++j)                                     \
                    acc[i][j] = __builtin_amdgcn_mfma_f32_16x16x32_bf16(        \
                        bfr[j], af[i], acc[i][j], 0, 0, 0);                     \
        }                                                                       \
        __syncthreads();                                                        \
    }

#define QSCALE 0.180336880f   // 0.125 * log2(e): folded into q for exp2 softmax

// QKV GEMM: N=3072. q,k,v all stored [b,h,t,dh] (v transposed later).
__global__ __launch_bounds__(256, 2) void gemm_qkv(
    const u16* __restrict__ A, const u16* __restrict__ Bt,
    const float* __restrict__ bias,
    u16* __restrict__ q, u16* __restrict__ k, u16* __restrict__ v)
{
    GEMM_MAINLOOP(A, Bt)
    const int colbase = n0 + wn;            // multiple of 64
    const int sel = colbase >> 10;          // wave-uniform: 0=q 1=k 2=v
    const int h = (colbase & 1023) >> 6;    // wave-uniform head
    u16* dst = (sel == 0) ? q : (sel == 1) ? k : v;
    const float scl = (sel == 0) ? QSCALE : 1.0f;
    #pragma unroll
    for (int j = 0; j < 4; ++j) {
        const int dh0 = j * 16 + 4 * g;                    // 0..63, 4-aligned
        const float4 bv4 = *reinterpret_cast<const float4*>(&bias[colbase + dh0]);
        #pragma unroll
        for (int i = 0; i < 4; ++i) {
            const int m = m0 + wm + i * 16 + lm;
            const int b = m >> 10, t = m & 1023;
            ushort4 o;
            o.x = f2bf((acc[i][j][0] + bv4.x) * scl);
            o.y = f2bf((acc[i][j][1] + bv4.y) * scl);
            o.z = f2bf((acc[i][j][2] + bv4.z) * scl);
            o.w = f2bf((acc[i][j][3] + bv4.w) * scl);
            *reinterpret_cast<ushort4*>(
                &dst[(((size_t)(b * NHEADS + h)) * SEQ + t) * DHEAD + dh0]) = o;
        }
    }
}

// Proj GEMM: N=1024. Epilogue: out = z + acc + bias (fp32, float4)
__global__ __launch_bounds__(256, 2) void gemm_proj(
    const u16* __restrict__ A, const u16* __restrict__ Bt,
    const float* __restrict__ bias, const float* __restrict__ z,
    float* __restrict__ out)
{
    GEMM_MAINLOOP(A, Bt)
    #pragma unroll
    for (int j = 0; j < 4; ++j) {
        const int col0 = n0 + wn + j * 16 + 4 * g;
        const float4 bv4 = *reinterpret_cast<const float4*>(&bias[col0]);
        #pragma unroll
        for (int i = 0; i < 4; ++i) {
            const int m = m0 + wm + i * 16 + lm;
            const size_t idx = (size_t)m * D_MODEL + col0;
            const float4 zv = *reinterpret_cast<const float4*>(&z[idx]);
            float4 ov;
            ov.x = zv.x + acc[i][j][0] + bv4.x;
            ov.y = zv.y + acc[i][j][1] + bv4.y;
            ov.z = zv.z + acc[i][j][2] + bv4.z;
            ov.w = zv.w + acc[i][j][3] + bv4.w;
            *reinterpret_cast<float4*>(&out[idx]) = ov;
        }
    }
}

// ------------------------------------------------------------ flash attention
// Transposed-S (S^T = K·Q^T), fixed-max softmax, 128 q-rows/block,
// x32 PV via tau-permuted V columns (r7, verified).
// New in r8: (1) Schraudolph bf16 exp2 — p_bf16 = low16((int)(s*128+16250.5)),
// ±3% rel err, full-rate VALU, and the SAME bits feed PV and the denominator
// so normalization is exact; (2) denominator via MFMA-of-ones (ones(16x32)·P
// sums all k per chunk — no VALU adds, no end shuffles); (3) register
// prefetch of next K/V tile right after the barrier (hides global latency).
#define KLD 68   // 64 + 4 pad halves (measured conflict-free r4/r6/r7)

__global__ __launch_bounds__(256, 2) void attn_kernel(
    const u16* __restrict__ Q, const u16* __restrict__ K,
    const u16* __restrict__ Vt, u16* __restrict__ msa)
{
    __shared__ u16 Ks[64 * KLD];
    __shared__ u16 Vs[64 * KLD];
    const int tid = threadIdx.x, wave = tid >> 6, lane = tid & 63;
    const int lm = lane & 15, g = lane >> 4;
    const int bi = blockIdx.x;
    const int bh = bi & 127;            // same XCD for all q-tiles of a head
    const int q0 = (bi >> 7) * 128;
    const int b = bh >> 4, h = bh & 15;
    const size_t headBase = (size_t)bh * SEQ * DHEAD;
    const u16* Qh = Q + headBase;
    const u16* Kh = K + headBase;
    const u16* Vh = Vt + headBase;      // [64 dh][1024 t]

    const int srow = tid >> 3, sseg = tid & 7;
    const int aA = 16 * (sseg >> 2) + 4 * (sseg & 3);   // tau-permute chunk

    const uint4 onesu = {0x3F803F80u, 0x3F803F80u, 0x3F803F80u, 0x3F803F80u};
    const bf16x8 ONES = __builtin_bit_cast(bf16x8, onesu);

    bf16x8 qf[2][2];
    #pragma unroll
    for (int s = 0; s < 2; ++s) {
        const u16* qrow = Qh + (size_t)(q0 + s * 64 + wave * 16 + lm) * DHEAD;
        qf[s][0] = *reinterpret_cast<const bf16x8*>(qrow + g * 8);
        qf[s][1] = *reinterpret_cast<const bf16x8*>(qrow + 32 + g * 8);
    }

    f32x4 o[2][4] = {};       // o[s][mt][r] = O^T[d = mt*16+4g+r][q subtile s]
    f32x4 lacc[2] = {};       // denominator accumulator (all rows identical)

    // prefetch tile 0 into registers
    uint4 kb[2]; uint2 va[2], vb[2];
    #pragma unroll
    for (int s2 = 0; s2 < 2; ++s2) {
        const int row = srow + 32 * s2;
        kb[s2] = *reinterpret_cast<const uint4*>(&Kh[(size_t)row * DHEAD + sseg * 8]);
        const u16* vrow = Vh + (size_t)row * SEQ;
        va[s2] = *reinterpret_cast<const uint2*>(vrow + aA);
        vb[s2] = *reinterpret_cast<const uint2*>(vrow + 32 + aA);
    }

    for (int j0 = 0; j0 < SEQ; j0 += 64) {
        // store staged registers to LDS
        #pragma unroll
        for (int s2 = 0; s2 < 2; ++s2) {
            const int row = srow + 32 * s2;
            *reinterpret_cast<uint4*>(&Ks[row * KLD + sseg * 8]) = kb[s2];
            uint4 wv; wv.x = va[s2].x; wv.y = va[s2].y; wv.z = vb[s2].x; wv.w = vb[s2].y;
            *reinterpret_cast<uint4*>(&Vs[row * KLD + sseg * 8]) = wv;
        }
        __syncthreads();

        // prefetch next tile (latency hidden behind this tile's compute)
        if (j0 + 64 < SEQ) {
            #pragma unroll
            for (int s2 = 0; s2 < 2; ++s2) {
                const int row = srow + 32 * s2;
                kb[s2] = *reinterpret_cast<const uint4*>(
                    &Kh[(size_t)(j0 + 64 + row) * DHEAD + sseg * 8]);
                const u16* vrow = Vh + (size_t)row * SEQ + j0 + 64;
                va[s2] = *reinterpret_cast<const uint2*>(vrow + aA);
                vb[s2] = *reinterpret_cast<const uint2*>(vrow + 32 + aA);
            }
        }

        // K-frags once (q-independent A-operands, shared by both subtiles)
        bf16x8 kf0[4], kf1[4];
        #pragma unroll
        for (int ni = 0; ni < 4; ++ni) {
            kf0[ni] = *reinterpret_cast<const bf16x8*>(&Ks[(ni*16 + lm) * KLD + g * 8]);
            kf1[ni] = *reinterpret_cast<const bf16x8*>(&Ks[(ni*16 + lm) * KLD + 32 + g * 8]);
        }

        bf16x8 pfr[2][2];
        #pragma unroll
        for (int s = 0; s < 2; ++s) {
            f32x4 st[4];
            #pragma unroll
            for (int ni = 0; ni < 4; ++ni) {
                f32x4 zero = {};
                st[ni] = __builtin_amdgcn_mfma_f32_16x16x32_bf16(kf0[ni], qf[s][0], zero, 0, 0, 0);
                st[ni] = __builtin_amdgcn_mfma_f32_16x16x32_bf16(kf1[ni], qf[s][1], st[ni], 0, 0, 0);
            }
            // Schraudolph: bf16(2^s) ~= low16((int)(s*128 + 16250.5))
            int ip[4][4];
            #pragma unroll
            for (int ni = 0; ni < 4; ++ni)
                #pragma unroll
                for (int r = 0; r < 4; ++r)
                    ip[ni][r] = (int)__builtin_fmaf(st[ni][r], 128.0f, 16250.5f);
            #pragma unroll
            for (int c = 0; c < 2; ++c) {
                uint4 u;
                u.x = pklo(ip[c][1],   ip[c][0]);
                u.y = pklo(ip[c][3],   ip[c][2]);
                u.z = pklo(ip[c+2][1], ip[c+2][0]);
                u.w = pklo(ip[c+2][3], ip[c+2][2]);
                pfr[s][c] = __builtin_bit_cast(bf16x8, u);
            }
            // denominator: ones(16x32)·P sums every k in the chunk
            lacc[s] = __builtin_amdgcn_mfma_f32_16x16x32_bf16(ONES, pfr[s][0], lacc[s], 0, 0, 0);
            lacc[s] = __builtin_amdgcn_mfma_f32_16x16x32_bf16(ONES, pfr[s][1], lacc[s], 0, 0, 0);
        }

        // O^T += V^T · P^T : A-frags (b128, q-independent) reused by both subtiles
        #pragma unroll
        for (int mt = 0; mt < 4; ++mt) {
            bf16x8 vf0 = *reinterpret_cast<const bf16x8*>(&Vs[(mt*16 + lm) * KLD + g * 8]);
            bf16x8 vf1 = *reinterpret_cast<const bf16x8*>(&Vs[(mt*16 + lm) * KLD + 32 + g * 8]);
            #pragma unroll
            for (int s = 0; s < 2; ++s) {
                o[s][mt] = __builtin_amdgcn_mfma_f32_16x16x32_bf16(vf0, pfr[s][0], o[s][mt], 0, 0, 0);
                o[s][mt] = __builtin_amdgcn_mfma_f32_16x16x32_bf16(vf1, pfr[s][1], o[s][mt], 0, 0, 0);
            }
        }
        __syncthreads();
    }

    #pragma unroll
    for (int s = 0; s < 2; ++s) {
        const float inv = 1.0f / lacc[s][0];   // full sum, identical across g
        const int t = q0 + s * 64 + wave * 16 + lm;
        const size_t base = ((size_t)b * SEQ + t) * D_MODEL + h * DHEAD;
        #pragma unroll
        for (int mt = 0; mt < 4; ++mt) {
            const int d0 = mt * 16 + 4 * g;
            ushort4 pk;
            pk.x = f2bf(o[s][mt][0] * inv);
            pk.y = f2bf(o[s][mt][1] * inv);
            pk.z = f2bf(o[s][mt][2] * inv);
            pk.w = f2bf(o[s][mt][3] * inv);
            *reinterpret_cast<ushort4*>(&msa[base + d0]) = pk;
        }
    }
}

// -------------------------------------------------------------------- launch
extern "C" void kernel_launch(void* const* d_in, const int* in_sizes, int n_in,
                              void* d_out, int out_size, void* d_ws, size_t ws_size,
                              hipStream_t stream) {
    const float* z      = (const float*)d_in[0];
    const float* ln_w   = (const float*)d_in[1];
    const float* ln_b   = (const float*)d_in[2];
    const float* W_qkv  = (const float*)d_in[3];
    const float* b_qkv  = (const float*)d_in[4];
    const float* W_proj = (const float*)d_in[5];
    const float* b_proj = (const float*)d_in[6];
    float* out = (float*)d_out;

    u16* ws = (u16*)d_ws;
    u16* zn     = ws;                              // [8192][1024] (aliased as msa later)
    u16* wqkvT  = zn + (size_t)MTOT * D_MODEL;     // [3072][1024]
    u16* wprojT = wqkvT + (size_t)3 * D_MODEL * D_MODEL;  // [1024][1024]
    u16* q      = wprojT + (size_t)D_MODEL * D_MODEL;     // [8][16][1024][64]
    u16* k      = q + (size_t)MTOT * D_MODEL;
    u16* vtmp   = k + (size_t)MTOT * D_MODEL;      // [b,h,t,dh]
    u16* vT     = vtmp + (size_t)MTOT * D_MODEL;   // [b,h,dh,t]
    u16* msa    = zn;   // reuse: zn consumed by gemm_qkv before attn writes

    ln_kernel<<<MTOT, 256, 0, stream>>>(z, ln_w, ln_b, zn);
    transpose_cast<<<dim3(3 * D_MODEL / 32, D_MODEL / 32), 256, 0, stream>>>(
        W_qkv, wqkvT, D_MODEL, 3 * D_MODEL);
    transpose_cast<<<dim3(D_MODEL / 32, D_MODEL / 32), 256, 0, stream>>>(
        W_proj, wprojT, D_MODEL, D_MODEL);
    gemm_qkv<<<dim3(3 * D_MODEL / 128, MTOT / 128), 256, 0, stream>>>(
        zn, wqkvT, b_qkv, q, k, vtmp);
    transpose_v<<<dim3(SEQ / 64, BATCH * NHEADS), 256, 0, stream>>>(vtmp, vT);
    attn_kernel<<<BATCH * NHEADS * (SEQ / 128), 256, 0, stream>>>(q, k, vT, msa);
    gemm_proj<<<dim3(D_MODEL / 128, MTOT / 128), 256, 0, stream>>>(
        msa, wprojT, b_proj, z, out);
}

// Round 9
// 252.574 us; speedup vs baseline: 1.1184x; 1.1184x over previous
//
#include <hip/hip_runtime.h>
#include <stdint.h>

typedef unsigned short u16;
typedef __bf16 bf16x8 __attribute__((ext_vector_type(8)));
typedef float f32x4 __attribute__((ext_vector_type(4)));

#define D_MODEL 1024
#define NHEADS  16
#define DHEAD   64
#define BATCH   8
#define SEQ     1024
#define MTOT    (BATCH*SEQ)          // 8192 rows

#define GPTR(p) ((const __attribute__((address_space(1))) void*)(p))
#define LPTR(p) ((__attribute__((address_space(3))) void*)(p))

__device__ __forceinline__ u16 f2bf(float f) {
    union { float f; uint32_t u; } v; v.f = f;
    uint32_t u = v.u;
    u += 0x7fffu + ((u >> 16) & 1u);  // RNE
    return (u16)(u >> 16);
}

// pack low16 of two ints: result = [i1.low16 : i0.low16] (i0 in low half)
__device__ __forceinline__ uint32_t pklo(int i1, int i0) {
    return __builtin_amdgcn_perm((uint32_t)i1, (uint32_t)i0, 0x05040100u);
}

// ---------------------------------------------------------------- LayerNorm
__global__ __launch_bounds__(256) void ln_kernel(
    const float* __restrict__ z, const float* __restrict__ w,
    const float* __restrict__ b, u16* __restrict__ zn)
{
    const int row = blockIdx.x;
    const int t = threadIdx.x;
    const float4 v = reinterpret_cast<const float4*>(z + (size_t)row * D_MODEL)[t];
    float s  = v.x + v.y + v.z + v.w;
    float s2 = v.x*v.x + v.y*v.y + v.z*v.z + v.w*v.w;
    #pragma unroll
    for (int off = 32; off; off >>= 1) {
        s  += __shfl_down(s,  off, 64);
        s2 += __shfl_down(s2, off, 64);
    }
    __shared__ float red[8];
    const int wave = t >> 6, lane = t & 63;
    if (lane == 0) { red[wave] = s; red[wave + 4] = s2; }
    __syncthreads();
    if (t == 0) {
        float ts  = red[0] + red[1] + red[2] + red[3];
        float ts2 = red[4] + red[5] + red[6] + red[7];
        float mu  = ts * (1.0f / D_MODEL);
        float var = ts2 * (1.0f / D_MODEL) - mu * mu;
        red[0] = mu; red[1] = rsqrtf(var + 1e-5f);
    }
    __syncthreads();
    const float mu = red[0], rstd = red[1];
    const float4 wv = reinterpret_cast<const float4*>(w)[t];
    const float4 bv = reinterpret_cast<const float4*>(b)[t];
    ushort4 o;
    o.x = f2bf((v.x - mu) * rstd * wv.x + bv.x);
    o.y = f2bf((v.y - mu) * rstd * wv.y + bv.y);
    o.z = f2bf((v.z - mu) * rstd * wv.z + bv.z);
    o.w = f2bf((v.w - mu) * rstd * wv.w + bv.w);
    reinterpret_cast<ushort4*>(zn + (size_t)row * D_MODEL)[t] = o;
}

// ----------------------------------------------- weight transpose + bf16 cast
__global__ __launch_bounds__(256) void transpose_cast(
    const float* __restrict__ in, u16* __restrict__ out, int R, int C)
{
    __shared__ u16 tile[32][33];
    const int c0 = blockIdx.x * 32, r0 = blockIdx.y * 32;
    const int tx = threadIdx.x & 31, ty = threadIdx.x >> 5;   // 32x8
    #pragma unroll
    for (int i = 0; i < 4; ++i)
        tile[ty + i*8][tx] = f2bf(in[(size_t)(r0 + ty + i*8) * C + c0 + tx]);
    __syncthreads();
    #pragma unroll
    for (int i = 0; i < 4; ++i)
        out[(size_t)(c0 + ty + i*8) * R + r0 + tx] = tile[tx][ty + i*8];
}

// -------------------------------------------------- V transpose: [b,h,t,dh] -> [b,h,dh,t]
__global__ __launch_bounds__(256) void transpose_v(
    const u16* __restrict__ in, u16* __restrict__ out)
{
    __shared__ u16 tile[64][65];
    const int bh = blockIdx.y;          // 0..127
    const int t0 = blockIdx.x * 64;     // 16 t-tiles
    const int tid = threadIdx.x;
    const u16* src = in + ((size_t)bh * SEQ + t0) * DHEAD;
    #pragma unroll
    for (int i = 0; i < 4; ++i) {
        const int row = (tid >> 4) + i * 16;       // t within tile
        const int c4  = (tid & 15) * 4;            // dh chunk
        *reinterpret_cast<ushort4*>(&tile[row][c4]) =
            *reinterpret_cast<const ushort4*>(&src[(size_t)row * DHEAD + c4]);
    }
    __syncthreads();
    u16* dst = out + (size_t)bh * DHEAD * SEQ + t0;
    #pragma unroll
    for (int i = 0; i < 4; ++i) {
        const int dh = (tid >> 4) + i * 16;
        const int tt = (tid & 15) * 4;
        ushort4 o;
        o.x = tile[tt+0][dh]; o.y = tile[tt+1][dh];
        o.z = tile[tt+2][dh]; o.w = tile[tt+3][dh];
        *reinterpret_cast<ushort4*>(&dst[(size_t)dh * SEQ + tt]) = o;
    }
}

// ---------------------------------------------------------------- GEMM core
// A [M][1024] bf16 row-major, Bt [N][1024] bf16, 128x128 tile, BK=64, 4 waves.
// global_load_lds width-16 staging; XOR swizzle (seg^(row&7)) -> conflict-free.
// MFMA operands SWAPPED (bfr first): acc[i][j][r] = C[m...lm][n...4g+r].
#define GEMM_MAINLOOP(A_, Bt_)                                                  \
    __shared__ u16 As[128 * 64];                                                \
    __shared__ u16 Bs[128 * 64];                                                \
    const int tid = threadIdx.x;                                                \
    const int wave = tid >> 6, lane = tid & 63;                                 \
    const int lm = lane & 15, g = lane >> 4;                                    \
    const int wm = (wave >> 1) * 64, wn = (wave & 1) * 64;                      \
    const int m0 = blockIdx.y * 128, n0 = blockIdx.x * 128;                     \
    const int srow = tid >> 3;                 /* 0..31 */                      \
    const int sseg = tid & 7;                                                   \
    const int sgcol = (sseg ^ (srow & 7)) * 8; /* swizzled global chunk */      \
    const int xl = lm & 7;                                                      \
    f32x4 acc[4][4] = {};                                                       \
    for (int k0 = 0; k0 < D_MODEL; k0 += 64) {                                  \
        _Pragma("unroll")                                                       \
        for (int c = 0; c < 4; ++c) {                                           \
            const int r = srow + c * 32;                                        \
            __builtin_amdgcn_global_load_lds(                                   \
                GPTR(&A_[(size_t)(m0 + r) * D_MODEL + k0 + sgcol]),             \
                LPTR(&As[r * 64 + sseg * 8]), 16, 0, 0);                        \
            __builtin_amdgcn_global_load_lds(                                   \
                GPTR(&Bt_[(size_t)(n0 + r) * D_MODEL + k0 + sgcol]),            \
                LPTR(&Bs[r * 64 + sseg * 8]), 16, 0, 0);                        \
        }                                                                       \
        __syncthreads();                                                        \
        _Pragma("unroll")                                                       \
        for (int ko = 0; ko < 2; ++ko) {                                        \
            const int ca = ((ko * 4 + g) ^ xl) * 8;                             \
            bf16x8 af[4], bfr[4];                                               \
            _Pragma("unroll")                                                   \
            for (int i = 0; i < 4; ++i) {                                       \
                af[i]  = *reinterpret_cast<const bf16x8*>(                      \
                    &As[(wm + i*16 + lm) * 64 + ca]);                           \
                bfr[i] = *reinterpret_cast<const bf16x8*>(                      \
                    &Bs[(wn + i*16 + lm) * 64 + ca]);                           \
            }                                                                   \
            _Pragma("unroll")                                                   \
            for (int i = 0; i < 4; ++i)                                         \
                _Pragma("unroll")                                               \
                for (int j = 0; j < 4; ++j)                                     \
                    acc[i][j] = __builtin_amdgcn_mfma_f32_16x16x32_bf16(        \
                        bfr[j], af[i], acc[i][j], 0, 0, 0);                     \
        }                                                                       \
        __syncthreads();                                                        \
    }

#define QSCALE 0.180336880f   // 0.125 * log2(e): folded into q for exp2 softmax

// QKV GEMM: N=3072. q,k,v all stored [b,h,t,dh] (v transposed later).
__global__ __launch_bounds__(256, 2) void gemm_qkv(
    const u16* __restrict__ A, const u16* __restrict__ Bt,
    const float* __restrict__ bias,
    u16* __restrict__ q, u16* __restrict__ k, u16* __restrict__ v)
{
    GEMM_MAINLOOP(A, Bt)
    const int colbase = n0 + wn;            // multiple of 64
    const int sel = colbase >> 10;          // wave-uniform: 0=q 1=k 2=v
    const int h = (colbase & 1023) >> 6;    // wave-uniform head
    u16* dst = (sel == 0) ? q : (sel == 1) ? k : v;
    const float scl = (sel == 0) ? QSCALE : 1.0f;
    #pragma unroll
    for (int j = 0; j < 4; ++j) {
        const int dh0 = j * 16 + 4 * g;                    // 0..63, 4-aligned
        const float4 bv4 = *reinterpret_cast<const float4*>(&bias[colbase + dh0]);
        #pragma unroll
        for (int i = 0; i < 4; ++i) {
            const int m = m0 + wm + i * 16 + lm;
            const int b = m >> 10, t = m & 1023;
            ushort4 o;
            o.x = f2bf((acc[i][j][0] + bv4.x) * scl);
            o.y = f2bf((acc[i][j][1] + bv4.y) * scl);
            o.z = f2bf((acc[i][j][2] + bv4.z) * scl);
            o.w = f2bf((acc[i][j][3] + bv4.w) * scl);
            *reinterpret_cast<ushort4*>(
                &dst[(((size_t)(b * NHEADS + h)) * SEQ + t) * DHEAD + dh0]) = o;
        }
    }
}

// Proj GEMM: N=1024. Epilogue: out = z + acc + bias (fp32, float4)
__global__ __launch_bounds__(256, 2) void gemm_proj(
    const u16* __restrict__ A, const u16* __restrict__ Bt,
    const float* __restrict__ bias, const float* __restrict__ z,
    float* __restrict__ out)
{
    GEMM_MAINLOOP(A, Bt)
    #pragma unroll
    for (int j = 0; j < 4; ++j) {
        const int col0 = n0 + wn + j * 16 + 4 * g;
        const float4 bv4 = *reinterpret_cast<const float4*>(&bias[col0]);
        #pragma unroll
        for (int i = 0; i < 4; ++i) {
            const int m = m0 + wm + i * 16 + lm;
            const size_t idx = (size_t)m * D_MODEL + col0;
            const float4 zv = *reinterpret_cast<const float4*>(&z[idx]);
            float4 ov;
            ov.x = zv.x + acc[i][j][0] + bv4.x;
            ov.y = zv.y + acc[i][j][1] + bv4.y;
            ov.z = zv.z + acc[i][j][2] + bv4.z;
            ov.w = zv.w + acc[i][j][3] + bv4.w;
            *reinterpret_cast<float4*>(&out[idx]) = ov;
        }
    }
}

// ------------------------------------------------------------ flash attention
// Transposed-S (S^T = K·Q^T), fixed-max softmax, 128 q-rows/block, x32 PV via
// tau-permuted V columns, Schraudolph bf16 exp2, denominator via MFMA-of-ones.
// r9: reverted r8's register prefetch (it raised VGPR 40->76, halved
// occupancy, and exposed latency — r8 post-mortem); staging is the r7-style
// direct global->LDS copy at loop top. launch_bounds back to (256,4).
#define KLD 68   // 64 + 4 pad halves (measured conflict-free r4/r6/r7)

__global__ __launch_bounds__(256, 4) void attn_kernel(
    const u16* __restrict__ Q, const u16* __restrict__ K,
    const u16* __restrict__ Vt, u16* __restrict__ msa)
{
    __shared__ u16 Ks[64 * KLD];
    __shared__ u16 Vs[64 * KLD];
    const int tid = threadIdx.x, wave = tid >> 6, lane = tid & 63;
    const int lm = lane & 15, g = lane >> 4;
    const int bi = blockIdx.x;
    const int bh = bi & 127;            // same XCD for all q-tiles of a head
    const int q0 = (bi >> 7) * 128;
    const int b = bh >> 4, h = bh & 15;
    const size_t headBase = (size_t)bh * SEQ * DHEAD;
    const u16* Qh = Q + headBase;
    const u16* Kh = K + headBase;
    const u16* Vh = Vt + headBase;      // [64 dh][1024 t]

    const int srow = tid >> 3, sseg = tid & 7;
    const int aA = 16 * (sseg >> 2) + 4 * (sseg & 3);   // tau-permute chunk

    const uint4 onesu = {0x3F803F80u, 0x3F803F80u, 0x3F803F80u, 0x3F803F80u};
    const bf16x8 ONES = __builtin_bit_cast(bf16x8, onesu);

    bf16x8 qf[2][2];
    #pragma unroll
    for (int s = 0; s < 2; ++s) {
        const u16* qrow = Qh + (size_t)(q0 + s * 64 + wave * 16 + lm) * DHEAD;
        qf[s][0] = *reinterpret_cast<const bf16x8*>(qrow + g * 8);
        qf[s][1] = *reinterpret_cast<const bf16x8*>(qrow + 32 + g * 8);
    }

    f32x4 o[2][4] = {};       // o[s][mt][r] = O^T[d = mt*16+4g+r][q subtile s]
    f32x4 lacc[2] = {};       // denominator accumulator (all rows identical)

    for (int j0 = 0; j0 < SEQ; j0 += 64) {
        // stage K and tau-permuted V directly global->LDS (r7 structure)
        #pragma unroll
        for (int s2 = 0; s2 < 2; ++s2) {
            const int row = srow + 32 * s2;
            *reinterpret_cast<uint4*>(&Ks[row * KLD + sseg * 8]) =
                *reinterpret_cast<const uint4*>(&Kh[(size_t)(j0 + row) * DHEAD + sseg * 8]);
            const u16* vrow = Vh + (size_t)row * SEQ + j0;
            const uint2 va = *reinterpret_cast<const uint2*>(vrow + aA);
            const uint2 vb = *reinterpret_cast<const uint2*>(vrow + 32 + aA);
            uint4 wv; wv.x = va.x; wv.y = va.y; wv.z = vb.x; wv.w = vb.y;
            *reinterpret_cast<uint4*>(&Vs[row * KLD + sseg * 8]) = wv;
        }
        __syncthreads();

        // K-frags once (q-independent A-operands, shared by both subtiles)
        bf16x8 kf0[4], kf1[4];
        #pragma unroll
        for (int ni = 0; ni < 4; ++ni) {
            kf0[ni] = *reinterpret_cast<const bf16x8*>(&Ks[(ni*16 + lm) * KLD + g * 8]);
            kf1[ni] = *reinterpret_cast<const bf16x8*>(&Ks[(ni*16 + lm) * KLD + 32 + g * 8]);
        }

        bf16x8 pfr[2][2];
        #pragma unroll
        for (int s = 0; s < 2; ++s) {
            f32x4 st[4];
            #pragma unroll
            for (int ni = 0; ni < 4; ++ni) {
                f32x4 zero = {};
                st[ni] = __builtin_amdgcn_mfma_f32_16x16x32_bf16(kf0[ni], qf[s][0], zero, 0, 0, 0);
                st[ni] = __builtin_amdgcn_mfma_f32_16x16x32_bf16(kf1[ni], qf[s][1], st[ni], 0, 0, 0);
            }
            // Schraudolph: bf16(2^s) ~= low16((int)(s*128 + 16250.5))
            int ip[4][4];
            #pragma unroll
            for (int ni = 0; ni < 4; ++ni)
                #pragma unroll
                for (int r = 0; r < 4; ++r)
                    ip[ni][r] = (int)__builtin_fmaf(st[ni][r], 128.0f, 16250.5f);
            #pragma unroll
            for (int c = 0; c < 2; ++c) {
                uint4 u;
                u.x = pklo(ip[c][1],   ip[c][0]);
                u.y = pklo(ip[c][3],   ip[c][2]);
                u.z = pklo(ip[c+2][1], ip[c+2][0]);
                u.w = pklo(ip[c+2][3], ip[c+2][2]);
                pfr[s][c] = __builtin_bit_cast(bf16x8, u);
            }
            // denominator: ones(16x32)·P sums every k in the chunk
            lacc[s] = __builtin_amdgcn_mfma_f32_16x16x32_bf16(ONES, pfr[s][0], lacc[s], 0, 0, 0);
            lacc[s] = __builtin_amdgcn_mfma_f32_16x16x32_bf16(ONES, pfr[s][1], lacc[s], 0, 0, 0);
        }

        // O^T += V^T · P^T : A-frags (b128, q-independent) reused by both subtiles
        #pragma unroll
        for (int mt = 0; mt < 4; ++mt) {
            bf16x8 vf0 = *reinterpret_cast<const bf16x8*>(&Vs[(mt*16 + lm) * KLD + g * 8]);
            bf16x8 vf1 = *reinterpret_cast<const bf16x8*>(&Vs[(mt*16 + lm) * KLD + 32 + g * 8]);
            #pragma unroll
            for (int s = 0; s < 2; ++s) {
                o[s][mt] = __builtin_amdgcn_mfma_f32_16x16x32_bf16(vf0, pfr[s][0], o[s][mt], 0, 0, 0);
                o[s][mt] = __builtin_amdgcn_mfma_f32_16x16x32_bf16(vf1, pfr[s][1], o[s][mt], 0, 0, 0);
            }
        }
        __syncthreads();
    }

    #pragma unroll
    for (int s = 0; s < 2; ++s) {
        const float inv = 1.0f / lacc[s][0];   // full sum, identical across g
        const int t = q0 + s * 64 + wave * 16 + lm;
        const size_t base = ((size_t)b * SEQ + t) * D_MODEL + h * DHEAD;
        #pragma unroll
        for (int mt = 0; mt < 4; ++mt) {
            const int d0 = mt * 16 + 4 * g;
            ushort4 pk;
            pk.x = f2bf(o[s][mt][0] * inv);
            pk.y = f2bf(o[s][mt][1] * inv);
            pk.z = f2bf(o[s][mt][2] * inv);
            pk.w = f2bf(o[s][mt][3] * inv);
            *reinterpret_cast<ushort4*>(&msa[base + d0]) = pk;
        }
    }
}

// -------------------------------------------------------------------- launch
extern "C" void kernel_launch(void* const* d_in, const int* in_sizes, int n_in,
                              void* d_out, int out_size, void* d_ws, size_t ws_size,
                              hipStream_t stream) {
    const float* z      = (const float*)d_in[0];
    const float* ln_w   = (const float*)d_in[1];
    const float* ln_b   = (const float*)d_in[2];
    const float* W_qkv  = (const float*)d_in[3];
    const float* b_qkv  = (const float*)d_in[4];
    const float* W_proj = (const float*)d_in[5];
    const float* b_proj = (const float*)d_in[6];
    float* out = (float*)d_out;

    u16* ws = (u16*)d_ws;
    u16* zn     = ws;                              // [8192][1024] (aliased as msa later)
    u16* wqkvT  = zn + (size_t)MTOT * D_MODEL;     // [3072][1024]
    u16* wprojT = wqkvT + (size_t)3 * D_MODEL * D_MODEL;  // [1024][1024]
    u16* q      = wprojT + (size_t)D_MODEL * D_MODEL;     // [8][16][1024][64]
    u16* k      = q + (size_t)MTOT * D_MODEL;
    u16* vtmp   = k + (size_t)MTOT * D_MODEL;      // [b,h,t,dh]
    u16* vT     = vtmp + (size_t)MTOT * D_MODEL;   // [b,h,dh,t]
    u16* msa    = zn;   // reuse: zn consumed by gemm_qkv before attn writes

    ln_kernel<<<MTOT, 256, 0, stream>>>(z, ln_w, ln_b, zn);
    transpose_cast<<<dim3(3 * D_MODEL / 32, D_MODEL / 32), 256, 0, stream>>>(
        W_qkv, wqkvT, D_MODEL, 3 * D_MODEL);
    transpose_cast<<<dim3(D_MODEL / 32, D_MODEL / 32), 256, 0, stream>>>(
        W_proj, wprojT, D_MODEL, D_MODEL);
    gemm_qkv<<<dim3(3 * D_MODEL / 128, MTOT / 128), 256, 0, stream>>>(
        zn, wqkvT, b_qkv, q, k, vtmp);
    transpose_v<<<dim3(SEQ / 64, BATCH * NHEADS), 256, 0, stream>>>(vtmp, vT);
    attn_kernel<<<BATCH * NHEADS * (SEQ / 128), 256, 0, stream>>>(q, k, vT, msa);
    gemm_proj<<<dim3(D_MODEL / 128, MTOT / 128), 256, 0, stream>>>(
        msa, wprojT, b_proj, z, out);
}

// Round 10
// 225.591 us; speedup vs baseline: 1.2521x; 1.1196x over previous
//
#include <hip/hip_runtime.h>
#include <stdint.h>

typedef unsigned short u16;
typedef uint8_t u8;
typedef __bf16 bf16x8 __attribute__((ext_vector_type(8)));
typedef float f32x4 __attribute__((ext_vector_type(4)));
typedef int i32x8 __attribute__((ext_vector_type(8)));

#define D_MODEL 1024
#define NHEADS  16
#define DHEAD   64
#define BATCH   8
#define SEQ     1024
#define MTOT    (BATCH*SEQ)          // 8192 rows

#define GPTR(p) ((const __attribute__((address_space(1))) void*)(p))
#define LPTR(p) ((__attribute__((address_space(3))) void*)(p))

// Device-only builtins (host pass just needs to parse — r2 lesson)
#if defined(__HIP_DEVICE_COMPILE__)
  #define MFMA_FP8_16x16x128(a, b, c) \
      __builtin_amdgcn_mfma_scale_f32_16x16x128_f8f6f4((a), (b), (c), 0, 0, 0, 127, 0, 127)
  #define CVT_PK_FP8(a, b, old, w) __builtin_amdgcn_cvt_pk_fp8_f32((a), (b), (old), (w))
#else
  #define MFMA_FP8_16x16x128(a, b, c) (c)
  #define CVT_PK_FP8(a, b, old, w) (0)
#endif

__device__ __forceinline__ u16 f2bf(float f) {
    union { float f; uint32_t u; } v; v.f = f;
    uint32_t u = v.u;
    u += 0x7fffu + ((u >> 16) & 1u);  // RNE
    return (u16)(u >> 16);
}

// pack low16 of two ints: result = [i1.low16 : i0.low16]
__device__ __forceinline__ uint32_t pklo(int i1, int i0) {
    return __builtin_amdgcn_perm((uint32_t)i1, (uint32_t)i0, 0x05040100u);
}

// ------------------------------------------------ LayerNorm -> fp8 e4m3 output
__global__ __launch_bounds__(256) void ln_kernel(
    const float* __restrict__ z, const float* __restrict__ w,
    const float* __restrict__ b, uint32_t* __restrict__ znf)
{
    const int row = blockIdx.x;
    const int t = threadIdx.x;
    const float4 v = reinterpret_cast<const float4*>(z + (size_t)row * D_MODEL)[t];
    float s  = v.x + v.y + v.z + v.w;
    float s2 = v.x*v.x + v.y*v.y + v.z*v.z + v.w*v.w;
    #pragma unroll
    for (int off = 32; off; off >>= 1) {
        s  += __shfl_down(s,  off, 64);
        s2 += __shfl_down(s2, off, 64);
    }
    __shared__ float red[8];
    const int wave = t >> 6, lane = t & 63;
    if (lane == 0) { red[wave] = s; red[wave + 4] = s2; }
    __syncthreads();
    if (t == 0) {
        float ts  = red[0] + red[1] + red[2] + red[3];
        float ts2 = red[4] + red[5] + red[6] + red[7];
        float mu  = ts * (1.0f / D_MODEL);
        float var = ts2 * (1.0f / D_MODEL) - mu * mu;
        red[0] = mu; red[1] = rsqrtf(var + 1e-5f);
    }
    __syncthreads();
    const float mu = red[0], rstd = red[1];
    const float4 wv = reinterpret_cast<const float4*>(w)[t];
    const float4 bv = reinterpret_cast<const float4*>(b)[t];
    const float x0 = (v.x - mu) * rstd * wv.x + bv.x;
    const float x1 = (v.y - mu) * rstd * wv.y + bv.y;
    const float x2 = (v.z - mu) * rstd * wv.z + bv.z;
    const float x3 = (v.w - mu) * rstd * wv.w + bv.w;
    int pk = CVT_PK_FP8(x0, x1, 0, false);
    pk = CVT_PK_FP8(x2, x3, pk, true);
    znf[(size_t)row * (D_MODEL / 4) + t] = (uint32_t)pk;
}

// --------------------------------- weight transpose + bf16 cast (for W_proj)
__global__ __launch_bounds__(256) void transpose_cast(
    const float* __restrict__ in, u16* __restrict__ out, int R, int C)
{
    __shared__ u16 tile[32][33];
    const int c0 = blockIdx.x * 32, r0 = blockIdx.y * 32;
    const int tx = threadIdx.x & 31, ty = threadIdx.x >> 5;   // 32x8
    #pragma unroll
    for (int i = 0; i < 4; ++i)
        tile[ty + i*8][tx] = f2bf(in[(size_t)(r0 + ty + i*8) * C + c0 + tx]);
    __syncthreads();
    #pragma unroll
    for (int i = 0; i < 4; ++i)
        out[(size_t)(c0 + ty + i*8) * R + r0 + tx] = tile[tx][ty + i*8];
}

// --------------------------------- weight transpose + fp8 cast (for W_qkv)
__global__ __launch_bounds__(256) void transpose_cast_fp8(
    const float* __restrict__ in, u8* __restrict__ out, int R, int C)
{
    __shared__ u8 tile[32][36];
    const int c0 = blockIdx.x * 32, r0 = blockIdx.y * 32;
    const int tx = threadIdx.x & 31, ty = threadIdx.x >> 5;   // 32x8
    #pragma unroll
    for (int i = 0; i < 4; ++i) {
        const float f = in[(size_t)(r0 + ty + i*8) * C + c0 + tx];
        tile[ty + i*8][tx] = (u8)(CVT_PK_FP8(f, 0.f, 0, false) & 0xFF);
    }
    __syncthreads();
    #pragma unroll
    for (int i = 0; i < 4; ++i)
        out[(size_t)(c0 + ty + i*8) * R + r0 + tx] = tile[tx][ty + i*8];
}

// -------------------------------------------------- V transpose: [b,h,t,dh] -> [b,h,dh,t]
__global__ __launch_bounds__(256) void transpose_v(
    const u16* __restrict__ in, u16* __restrict__ out)
{
    __shared__ u16 tile[64][65];
    const int bh = blockIdx.y;          // 0..127
    const int t0 = blockIdx.x * 64;     // 16 t-tiles
    const int tid = threadIdx.x;
    const u16* src = in + ((size_t)bh * SEQ + t0) * DHEAD;
    #pragma unroll
    for (int i = 0; i < 4; ++i) {
        const int row = (tid >> 4) + i * 16;       // t within tile
        const int c4  = (tid & 15) * 4;            // dh chunk
        *reinterpret_cast<ushort4*>(&tile[row][c4]) =
            *reinterpret_cast<const ushort4*>(&src[(size_t)row * DHEAD + c4]);
    }
    __syncthreads();
    u16* dst = out + (size_t)bh * DHEAD * SEQ + t0;
    #pragma unroll
    for (int i = 0; i < 4; ++i) {
        const int dh = (tid >> 4) + i * 16;
        const int tt = (tid & 15) * 4;
        ushort4 o;
        o.x = tile[tt+0][dh]; o.y = tile[tt+1][dh];
        o.z = tile[tt+2][dh]; o.w = tile[tt+3][dh];
        *reinterpret_cast<ushort4*>(&dst[(size_t)dh * SEQ + tt]) = o;
    }
}

#define QSCALE 0.180336880f   // 0.125 * log2(e): folded into q for exp2 softmax

// ------------------------------------------------------- QKV GEMM (fp8 MX)
// A [M][1024] fp8 e4m3, Bt [N][1024] fp8. 128x128 tile, K-tile=128 bytes,
// 4 waves x 64x64. MFMA: mfma_scale_f32_16x16x128_f8f6f4, unit scales (127),
// operand-swapped (weights as A-op) -> C layout identical to the bf16 path
// (shape-determined, m121-128). global_load_lds: LDS addr == lane*16 exactly.
// XOR swizzle (chunk^(row&7)) spreads the 128B-stride rows over all banks.
__global__ __launch_bounds__(256, 2) void gemm_qkv(
    const u8* __restrict__ A, const u8* __restrict__ Bt,
    const float* __restrict__ bias,
    u16* __restrict__ q, u16* __restrict__ k, u16* __restrict__ v)
{
    __shared__ u8 As[128 * 128];
    __shared__ u8 Bs[128 * 128];
    const int tid = threadIdx.x;
    const int wave = tid >> 6, lane = tid & 63;
    const int lm = lane & 15, g = lane >> 4;
    const int wm = (wave >> 1) * 64, wn = (wave & 1) * 64;
    const int m0 = blockIdx.y * 128, n0 = blockIdx.x * 128;
    const int srow = tid >> 3;                  // 0..31
    const int sseg = tid & 7;                   // 8 chunks of 16B per 128B row
    const int sgcol = (sseg ^ (srow & 7)) * 16; // swizzled global byte offset
    const int xl = lm & 7;
    const int ca0 = ((2 * g) ^ xl) * 16;        // frag bytes 0-15 (swizzled)
    const int ca1 = ((2 * g + 1) ^ xl) * 16;    // frag bytes 16-31
    f32x4 acc[4][4] = {};
    for (int k0 = 0; k0 < D_MODEL; k0 += 128) {
        #pragma unroll
        for (int c = 0; c < 4; ++c) {
            const int r = srow + c * 32;
            __builtin_amdgcn_global_load_lds(
                GPTR(&A[(size_t)(m0 + r) * D_MODEL + k0 + sgcol]),
                LPTR(&As[r * 128 + sseg * 16]), 16, 0, 0);
            __builtin_amdgcn_global_load_lds(
                GPTR(&Bt[(size_t)(n0 + r) * D_MODEL + k0 + sgcol]),
                LPTR(&Bs[r * 128 + sseg * 16]), 16, 0, 0);
        }
        __syncthreads();
        i32x8 af[4], bfr[4];
        #pragma unroll
        for (int i = 0; i < 4; ++i) {
            const uint4 alo = *reinterpret_cast<const uint4*>(&As[(wm + i*16 + lm) * 128 + ca0]);
            const uint4 ahi = *reinterpret_cast<const uint4*>(&As[(wm + i*16 + lm) * 128 + ca1]);
            af[i][0] = alo.x; af[i][1] = alo.y; af[i][2] = alo.z; af[i][3] = alo.w;
            af[i][4] = ahi.x; af[i][5] = ahi.y; af[i][6] = ahi.z; af[i][7] = ahi.w;
            const uint4 blo = *reinterpret_cast<const uint4*>(&Bs[(wn + i*16 + lm) * 128 + ca0]);
            const uint4 bhi = *reinterpret_cast<const uint4*>(&Bs[(wn + i*16 + lm) * 128 + ca1]);
            bfr[i][0] = blo.x; bfr[i][1] = blo.y; bfr[i][2] = blo.z; bfr[i][3] = blo.w;
            bfr[i][4] = bhi.x; bfr[i][5] = bhi.y; bfr[i][6] = bhi.z; bfr[i][7] = bhi.w;
        }
        #pragma unroll
        for (int i = 0; i < 4; ++i)
            #pragma unroll
            for (int j = 0; j < 4; ++j)
                acc[i][j] = MFMA_FP8_16x16x128(bfr[j], af[i], acc[i][j]);
        __syncthreads();
    }
    const int colbase = n0 + wn;            // multiple of 64
    const int sel = colbase >> 10;          // wave-uniform: 0=q 1=k 2=v
    const int h = (colbase & 1023) >> 6;    // wave-uniform head
    u16* dst = (sel == 0) ? q : (sel == 1) ? k : v;
    const float scl = (sel == 0) ? QSCALE : 1.0f;
    #pragma unroll
    for (int j = 0; j < 4; ++j) {
        const int dh0 = j * 16 + 4 * g;
        const float4 bv4 = *reinterpret_cast<const float4*>(&bias[colbase + dh0]);
        #pragma unroll
        for (int i = 0; i < 4; ++i) {
            const int m = m0 + wm + i * 16 + lm;
            const int b = m >> 10, t = m & 1023;
            ushort4 o;
            o.x = f2bf((acc[i][j][0] + bv4.x) * scl);
            o.y = f2bf((acc[i][j][1] + bv4.y) * scl);
            o.z = f2bf((acc[i][j][2] + bv4.z) * scl);
            o.w = f2bf((acc[i][j][3] + bv4.w) * scl);
            *reinterpret_cast<ushort4*>(
                &dst[(((size_t)(b * NHEADS + h)) * SEQ + t) * DHEAD + dh0]) = o;
        }
    }
}

// ------------------------------------------------------- Proj GEMM (bf16)
// unchanged r9 structure: 128x128, BK=64, global_load_lds + XOR swizzle.
__global__ __launch_bounds__(256, 2) void gemm_proj(
    const u16* __restrict__ A, const u16* __restrict__ Bt,
    const float* __restrict__ bias, const float* __restrict__ z,
    float* __restrict__ out)
{
    __shared__ u16 As[128 * 64];
    __shared__ u16 Bs[128 * 64];
    const int tid = threadIdx.x;
    const int wave = tid >> 6, lane = tid & 63;
    const int lm = lane & 15, g = lane >> 4;
    const int wm = (wave >> 1) * 64, wn = (wave & 1) * 64;
    const int m0 = blockIdx.y * 128, n0 = blockIdx.x * 128;
    const int srow = tid >> 3;
    const int sseg = tid & 7;
    const int sgcol = (sseg ^ (srow & 7)) * 8;
    const int xl = lm & 7;
    f32x4 acc[4][4] = {};
    for (int k0 = 0; k0 < D_MODEL; k0 += 64) {
        #pragma unroll
        for (int c = 0; c < 4; ++c) {
            const int r = srow + c * 32;
            __builtin_amdgcn_global_load_lds(
                GPTR(&A[(size_t)(m0 + r) * D_MODEL + k0 + sgcol]),
                LPTR(&As[r * 64 + sseg * 8]), 16, 0, 0);
            __builtin_amdgcn_global_load_lds(
                GPTR(&Bt[(size_t)(n0 + r) * D_MODEL + k0 + sgcol]),
                LPTR(&Bs[r * 64 + sseg * 8]), 16, 0, 0);
        }
        __syncthreads();
        #pragma unroll
        for (int ko = 0; ko < 2; ++ko) {
            const int ca = ((ko * 4 + g) ^ xl) * 8;
            bf16x8 af[4], bfr[4];
            #pragma unroll
            for (int i = 0; i < 4; ++i) {
                af[i]  = *reinterpret_cast<const bf16x8*>(&As[(wm + i*16 + lm) * 64 + ca]);
                bfr[i] = *reinterpret_cast<const bf16x8*>(&Bs[(wn + i*16 + lm) * 64 + ca]);
            }
            #pragma unroll
            for (int i = 0; i < 4; ++i)
                #pragma unroll
                for (int j = 0; j < 4; ++j)
                    acc[i][j] = __builtin_amdgcn_mfma_f32_16x16x32_bf16(
                        bfr[j], af[i], acc[i][j], 0, 0, 0);
        }
        __syncthreads();
    }
    #pragma unroll
    for (int j = 0; j < 4; ++j) {
        const int col0 = n0 + wn + j * 16 + 4 * g;
        const float4 bv4 = *reinterpret_cast<const float4*>(&bias[col0]);
        #pragma unroll
        for (int i = 0; i < 4; ++i) {
            const int m = m0 + wm + i * 16 + lm;
            const size_t idx = (size_t)m * D_MODEL + col0;
            const float4 zv = *reinterpret_cast<const float4*>(&z[idx]);
            float4 ov;
            ov.x = zv.x + acc[i][j][0] + bv4.x;
            ov.y = zv.y + acc[i][j][1] + bv4.y;
            ov.z = zv.z + acc[i][j][2] + bv4.z;
            ov.w = zv.w + acc[i][j][3] + bv4.w;
            *reinterpret_cast<float4*>(&out[idx]) = ov;
        }
    }
}

// ------------------------------------------------------------ flash attention
// r9 kernel unchanged: transposed-S, fixed-max softmax, 128 q-rows/block,
// x32 PV via tau-permuted V, Schraudolph bf16 exp2, MFMA-of-ones denominator.
#define KLD 68   // 64 + 4 pad halves (measured conflict-free r4/r6/r7)

__global__ __launch_bounds__(256, 4) void attn_kernel(
    const u16* __restrict__ Q, const u16* __restrict__ K,
    const u16* __restrict__ Vt, u16* __restrict__ msa)
{
    __shared__ u16 Ks[64 * KLD];
    __shared__ u16 Vs[64 * KLD];
    const int tid = threadIdx.x, wave = tid >> 6, lane = tid & 63;
    const int lm = lane & 15, g = lane >> 4;
    const int bi = blockIdx.x;
    const int bh = bi & 127;            // same XCD for all q-tiles of a head
    const int q0 = (bi >> 7) * 128;
    const int b = bh >> 4, h = bh & 15;
    const size_t headBase = (size_t)bh * SEQ * DHEAD;
    const u16* Qh = Q + headBase;
    const u16* Kh = K + headBase;
    const u16* Vh = Vt + headBase;      // [64 dh][1024 t]

    const int srow = tid >> 3, sseg = tid & 7;
    const int aA = 16 * (sseg >> 2) + 4 * (sseg & 3);   // tau-permute chunk

    const uint4 onesu = {0x3F803F80u, 0x3F803F80u, 0x3F803F80u, 0x3F803F80u};
    const bf16x8 ONES = __builtin_bit_cast(bf16x8, onesu);

    bf16x8 qf[2][2];
    #pragma unroll
    for (int s = 0; s < 2; ++s) {
        const u16* qrow = Qh + (size_t)(q0 + s * 64 + wave * 16 + lm) * DHEAD;
        qf[s][0] = *reinterpret_cast<const bf16x8*>(qrow + g * 8);
        qf[s][1] = *reinterpret_cast<const bf16x8*>(qrow + 32 + g * 8);
    }

    f32x4 o[2][4] = {};
    f32x4 lacc[2] = {};

    for (int j0 = 0; j0 < SEQ; j0 += 64) {
        #pragma unroll
        for (int s2 = 0; s2 < 2; ++s2) {
            const int row = srow + 32 * s2;
            *reinterpret_cast<uint4*>(&Ks[row * KLD + sseg * 8]) =
                *reinterpret_cast<const uint4*>(&Kh[(size_t)(j0 + row) * DHEAD + sseg * 8]);
            const u16* vrow = Vh + (size_t)row * SEQ + j0;
            const uint2 va = *reinterpret_cast<const uint2*>(vrow + aA);
            const uint2 vb = *reinterpret_cast<const uint2*>(vrow + 32 + aA);
            uint4 wv; wv.x = va.x; wv.y = va.y; wv.z = vb.x; wv.w = vb.y;
            *reinterpret_cast<uint4*>(&Vs[row * KLD + sseg * 8]) = wv;
        }
        __syncthreads();

        bf16x8 kf0[4], kf1[4];
        #pragma unroll
        for (int ni = 0; ni < 4; ++ni) {
            kf0[ni] = *reinterpret_cast<const bf16x8*>(&Ks[(ni*16 + lm) * KLD + g * 8]);
            kf1[ni] = *reinterpret_cast<const bf16x8*>(&Ks[(ni*16 + lm) * KLD + 32 + g * 8]);
        }

        bf16x8 pfr[2][2];
        #pragma unroll
        for (int s = 0; s < 2; ++s) {
            f32x4 st[4];
            #pragma unroll
            for (int ni = 0; ni < 4; ++ni) {
                f32x4 zero = {};
                st[ni] = __builtin_amdgcn_mfma_f32_16x16x32_bf16(kf0[ni], qf[s][0], zero, 0, 0, 0);
                st[ni] = __builtin_amdgcn_mfma_f32_16x16x32_bf16(kf1[ni], qf[s][1], st[ni], 0, 0, 0);
            }
            int ip[4][4];
            #pragma unroll
            for (int ni = 0; ni < 4; ++ni)
                #pragma unroll
                for (int r = 0; r < 4; ++r)
                    ip[ni][r] = (int)__builtin_fmaf(st[ni][r], 128.0f, 16250.5f);
            #pragma unroll
            for (int c = 0; c < 2; ++c) {
                uint4 u;
                u.x = pklo(ip[c][1],   ip[c][0]);
                u.y = pklo(ip[c][3],   ip[c][2]);
                u.z = pklo(ip[c+2][1], ip[c+2][0]);
                u.w = pklo(ip[c+2][3], ip[c+2][2]);
                pfr[s][c] = __builtin_bit_cast(bf16x8, u);
            }
            lacc[s] = __builtin_amdgcn_mfma_f32_16x16x32_bf16(ONES, pfr[s][0], lacc[s], 0, 0, 0);
            lacc[s] = __builtin_amdgcn_mfma_f32_16x16x32_bf16(ONES, pfr[s][1], lacc[s], 0, 0, 0);
        }

        #pragma unroll
        for (int mt = 0; mt < 4; ++mt) {
            bf16x8 vf0 = *reinterpret_cast<const bf16x8*>(&Vs[(mt*16 + lm) * KLD + g * 8]);
            bf16x8 vf1 = *reinterpret_cast<const bf16x8*>(&Vs[(mt*16 + lm) * KLD + 32 + g * 8]);
            #pragma unroll
            for (int s = 0; s < 2; ++s) {
                o[s][mt] = __builtin_amdgcn_mfma_f32_16x16x32_bf16(vf0, pfr[s][0], o[s][mt], 0, 0, 0);
                o[s][mt] = __builtin_amdgcn_mfma_f32_16x16x32_bf16(vf1, pfr[s][1], o[s][mt], 0, 0, 0);
            }
        }
        __syncthreads();
    }

    #pragma unroll
    for (int s = 0; s < 2; ++s) {
        const float inv = 1.0f / lacc[s][0];
        const int t = q0 + s * 64 + wave * 16 + lm;
        const size_t base = ((size_t)b * SEQ + t) * D_MODEL + h * DHEAD;
        #pragma unroll
        for (int mt = 0; mt < 4; ++mt) {
            const int d0 = mt * 16 + 4 * g;
            ushort4 pk;
            pk.x = f2bf(o[s][mt][0] * inv);
            pk.y = f2bf(o[s][mt][1] * inv);
            pk.z = f2bf(o[s][mt][2] * inv);
            pk.w = f2bf(o[s][mt][3] * inv);
            *reinterpret_cast<ushort4*>(&msa[base + d0]) = pk;
        }
    }
}

// -------------------------------------------------------------------- launch
extern "C" void kernel_launch(void* const* d_in, const int* in_sizes, int n_in,
                              void* d_out, int out_size, void* d_ws, size_t ws_size,
                              hipStream_t stream) {
    const float* z      = (const float*)d_in[0];
    const float* ln_w   = (const float*)d_in[1];
    const float* ln_b   = (const float*)d_in[2];
    const float* W_qkv  = (const float*)d_in[3];
    const float* b_qkv  = (const float*)d_in[4];
    const float* W_proj = (const float*)d_in[5];
    const float* b_proj = (const float*)d_in[6];
    float* out = (float*)d_out;

    u8* ws = (u8*)d_ws;
    u8*  znf    = ws;                                       // fp8 [8192][1024]  8 MB
    u8*  wqkvTf = znf + (size_t)MTOT * D_MODEL;             // fp8 [3072][1024]  3 MB
    u16* wprojT = (u16*)(wqkvTf + (size_t)3 * D_MODEL * D_MODEL);  // bf16 [1024][1024]
    u16* q      = wprojT + (size_t)D_MODEL * D_MODEL;       // bf16 [8][16][1024][64]
    u16* k      = q + (size_t)MTOT * D_MODEL;
    u16* vtmp   = k + (size_t)MTOT * D_MODEL;               // [b,h,t,dh]; reused as msa
    u16* vT     = vtmp + (size_t)MTOT * D_MODEL;            // [b,h,dh,t]
    u16* msa    = vtmp;  // vtmp consumed by transpose_v before attn writes msa

    ln_kernel<<<MTOT, 256, 0, stream>>>(z, ln_w, ln_b, (uint32_t*)znf);
    transpose_cast_fp8<<<dim3(3 * D_MODEL / 32, D_MODEL / 32), 256, 0, stream>>>(
        W_qkv, wqkvTf, D_MODEL, 3 * D_MODEL);
    transpose_cast<<<dim3(D_MODEL / 32, D_MODEL / 32), 256, 0, stream>>>(
        W_proj, wprojT, D_MODEL, D_MODEL);
    gemm_qkv<<<dim3(3 * D_MODEL / 128, MTOT / 128), 256, 0, stream>>>(
        znf, wqkvTf, b_qkv, q, k, vtmp);
    transpose_v<<<dim3(SEQ / 64, BATCH * NHEADS), 256, 0, stream>>>(vtmp, vT);
    attn_kernel<<<BATCH * NHEADS * (SEQ / 128), 256, 0, stream>>>(q, k, vT, msa);
    gemm_proj<<<dim3(D_MODEL / 128, MTOT / 128), 256, 0, stream>>>(
        msa, wprojT, b_proj, z, out);
}

// Round 11
// 206.424 us; speedup vs baseline: 1.3684x; 1.0929x over previous
//
#include <hip/hip_runtime.h>
#include <stdint.h>

typedef unsigned short u16;
typedef uint8_t u8;
typedef __bf16 bf16x8 __attribute__((ext_vector_type(8)));
typedef float f32x4 __attribute__((ext_vector_type(4)));
typedef int i32x8 __attribute__((ext_vector_type(8)));

#define D_MODEL 1024
#define NHEADS  16
#define DHEAD   64
#define BATCH   8
#define SEQ     1024
#define MTOT    (BATCH*SEQ)          // 8192 rows

#define GPTR(p) ((const __attribute__((address_space(1))) void*)(p))
#define LPTR(p) ((__attribute__((address_space(3))) void*)(p))

// Device-only builtins (host pass just needs to parse — r2 lesson)
#if defined(__HIP_DEVICE_COMPILE__)
  #define MFMA_FP8_16x16x128(a, b, c) \
      __builtin_amdgcn_mfma_scale_f32_16x16x128_f8f6f4((a), (b), (c), 0, 0, 0, 127, 0, 127)
  #define CVT_PK_FP8(a, b, old, w) __builtin_amdgcn_cvt_pk_fp8_f32((a), (b), (old), (w))
#else
  #define MFMA_FP8_16x16x128(a, b, c) (c)
  #define CVT_PK_FP8(a, b, old, w) (0)
#endif

__device__ __forceinline__ u16 f2bf(float f) {
    union { float f; uint32_t u; } v; v.f = f;
    uint32_t u = v.u;
    u += 0x7fffu + ((u >> 16) & 1u);  // RNE
    return (u16)(u >> 16);
}

// pack low16 of two ints: result = [i1.low16 : i0.low16]
__device__ __forceinline__ uint32_t pklo(int i1, int i0) {
    return __builtin_amdgcn_perm((uint32_t)i1, (uint32_t)i0, 0x05040100u);
}

// ------------------------------------------------ LayerNorm -> fp8 e4m3 output
__global__ __launch_bounds__(256) void ln_kernel(
    const float* __restrict__ z, const float* __restrict__ w,
    const float* __restrict__ b, uint32_t* __restrict__ znf)
{
    const int row = blockIdx.x;
    const int t = threadIdx.x;
    const float4 v = reinterpret_cast<const float4*>(z + (size_t)row * D_MODEL)[t];
    float s  = v.x + v.y + v.z + v.w;
    float s2 = v.x*v.x + v.y*v.y + v.z*v.z + v.w*v.w;
    #pragma unroll
    for (int off = 32; off; off >>= 1) {
        s  += __shfl_down(s,  off, 64);
        s2 += __shfl_down(s2, off, 64);
    }
    __shared__ float red[8];
    const int wave = t >> 6, lane = t & 63;
    if (lane == 0) { red[wave] = s; red[wave + 4] = s2; }
    __syncthreads();
    if (t == 0) {
        float ts  = red[0] + red[1] + red[2] + red[3];
        float ts2 = red[4] + red[5] + red[6] + red[7];
        float mu  = ts * (1.0f / D_MODEL);
        float var = ts2 * (1.0f / D_MODEL) - mu * mu;
        red[0] = mu; red[1] = rsqrtf(var + 1e-5f);
    }
    __syncthreads();
    const float mu = red[0], rstd = red[1];
    const float4 wv = reinterpret_cast<const float4*>(w)[t];
    const float4 bv = reinterpret_cast<const float4*>(b)[t];
    const float x0 = (v.x - mu) * rstd * wv.x + bv.x;
    const float x1 = (v.y - mu) * rstd * wv.y + bv.y;
    const float x2 = (v.z - mu) * rstd * wv.z + bv.z;
    const float x3 = (v.w - mu) * rstd * wv.w + bv.w;
    int pk = CVT_PK_FP8(x0, x1, 0, false);
    pk = CVT_PK_FP8(x2, x3, pk, true);
    znf[(size_t)row * (D_MODEL / 4) + t] = (uint32_t)pk;
}

// --------------- merged weight prep: transpose + fp8 cast for BOTH weights
// grid (128, 32): x<96 -> W_qkv (C=3072), else W_proj (C=1024)
__global__ __launch_bounds__(256) void prep_weights(
    const float* __restrict__ Wqkv, const float* __restrict__ Wproj,
    u8* __restrict__ outQkv, u8* __restrict__ outProj)
{
    __shared__ u8 tile[32][36];
    const int bx = blockIdx.x;
    const float* in; u8* out; int C;
    if (bx < 96) { in = Wqkv;  out = outQkv;  C = 3072; }
    else         { in = Wproj; out = outProj; C = 1024; }
    const int c0 = (bx < 96 ? bx : bx - 96) * 32, r0 = blockIdx.y * 32;
    const int tx = threadIdx.x & 31, ty = threadIdx.x >> 5;   // 32x8
    #pragma unroll
    for (int i = 0; i < 4; ++i) {
        const float f = in[(size_t)(r0 + ty + i*8) * C + c0 + tx];
        tile[ty + i*8][tx] = (u8)(CVT_PK_FP8(f, 0.f, 0, false) & 0xFF);
    }
    __syncthreads();
    #pragma unroll
    for (int i = 0; i < 4; ++i)
        out[(size_t)(c0 + ty + i*8) * D_MODEL + r0 + tx] = tile[tx][ty + i*8];
}

#define QSCALE 0.180336880f   // 0.125 * log2(e): folded into q for exp2 softmax

// ------------------------------------------------------- QKV GEMM (fp8 MX)
// 128x128 tile, K-tile=128B, 4 waves. XOR swizzle; global_load_lds width-16.
// q/k blocks (bx<16): operand-SWAPPED -> lane owns 4 consecutive cols (dh).
// v blocks (bx>=16): UNSWAPPED (r3-verified layout) -> lane owns 4 consecutive
// tokens -> epilogue writes vT[b,h,dh,t] directly (ushort4 of 4 t). This
// removes the separate transpose_v kernel.
__global__ __launch_bounds__(256, 2) void gemm_qkv(
    const u8* __restrict__ A, const u8* __restrict__ Bt,
    const float* __restrict__ bias,
    u16* __restrict__ q, u16* __restrict__ k, u16* __restrict__ vT)
{
    __shared__ u8 As[128 * 128];
    __shared__ u8 Bs[128 * 128];
    const int tid = threadIdx.x;
    const int wave = tid >> 6, lane = tid & 63;
    const int lm = lane & 15, g = lane >> 4;
    const int wm = (wave >> 1) * 64, wn = (wave & 1) * 64;
    const int m0 = blockIdx.y * 128, n0 = blockIdx.x * 128;
    const int srow = tid >> 3;
    const int sseg = tid & 7;
    const int sgcol = (sseg ^ (srow & 7)) * 16;
    const int xl = lm & 7;
    const int ca0 = ((2 * g) ^ xl) * 16;
    const int ca1 = ((2 * g + 1) ^ xl) * 16;
    const bool isV = (blockIdx.x >= 16);
    f32x4 acc[4][4] = {};
    for (int k0 = 0; k0 < D_MODEL; k0 += 128) {
        #pragma unroll
        for (int c = 0; c < 4; ++c) {
            const int r = srow + c * 32;
            __builtin_amdgcn_global_load_lds(
                GPTR(&A[(size_t)(m0 + r) * D_MODEL + k0 + sgcol]),
                LPTR(&As[r * 128 + sseg * 16]), 16, 0, 0);
            __builtin_amdgcn_global_load_lds(
                GPTR(&Bt[(size_t)(n0 + r) * D_MODEL + k0 + sgcol]),
                LPTR(&Bs[r * 128 + sseg * 16]), 16, 0, 0);
        }
        __syncthreads();
        i32x8 af[4], bfr[4];
        #pragma unroll
        for (int i = 0; i < 4; ++i) {
            const uint4 alo = *reinterpret_cast<const uint4*>(&As[(wm + i*16 + lm) * 128 + ca0]);
            const uint4 ahi = *reinterpret_cast<const uint4*>(&As[(wm + i*16 + lm) * 128 + ca1]);
            af[i][0] = alo.x; af[i][1] = alo.y; af[i][2] = alo.z; af[i][3] = alo.w;
            af[i][4] = ahi.x; af[i][5] = ahi.y; af[i][6] = ahi.z; af[i][7] = ahi.w;
            const uint4 blo = *reinterpret_cast<const uint4*>(&Bs[(wn + i*16 + lm) * 128 + ca0]);
            const uint4 bhi = *reinterpret_cast<const uint4*>(&Bs[(wn + i*16 + lm) * 128 + ca1]);
            bfr[i][0] = blo.x; bfr[i][1] = blo.y; bfr[i][2] = blo.z; bfr[i][3] = blo.w;
            bfr[i][4] = bhi.x; bfr[i][5] = bhi.y; bfr[i][6] = bhi.z; bfr[i][7] = bhi.w;
        }
        if (!isV) {
            #pragma unroll
            for (int i = 0; i < 4; ++i)
                #pragma unroll
                for (int j = 0; j < 4; ++j)
                    acc[i][j] = MFMA_FP8_16x16x128(bfr[j], af[i], acc[i][j]);
        } else {
            #pragma unroll
            for (int i = 0; i < 4; ++i)
                #pragma unroll
                for (int j = 0; j < 4; ++j)
                    acc[i][j] = MFMA_FP8_16x16x128(af[i], bfr[j], acc[i][j]);
        }
        __syncthreads();
    }
    const int colbase = n0 + wn;            // multiple of 64
    const int h = (colbase & 1023) >> 6;    // wave-uniform head
    if (!isV) {
        const int sel = colbase >> 10;      // 0=q 1=k
        u16* dst = (sel == 0) ? q : k;
        const float scl = (sel == 0) ? QSCALE : 1.0f;
        #pragma unroll
        for (int j = 0; j < 4; ++j) {
            const int dh0 = j * 16 + 4 * g;
            const float4 bv4 = *reinterpret_cast<const float4*>(&bias[colbase + dh0]);
            #pragma unroll
            for (int i = 0; i < 4; ++i) {
                const int m = m0 + wm + i * 16 + lm;
                const int b = m >> 10, t = m & 1023;
                ushort4 o;
                o.x = f2bf((acc[i][j][0] + bv4.x) * scl);
                o.y = f2bf((acc[i][j][1] + bv4.y) * scl);
                o.z = f2bf((acc[i][j][2] + bv4.z) * scl);
                o.w = f2bf((acc[i][j][3] + bv4.w) * scl);
                *reinterpret_cast<ushort4*>(
                    &dst[(((size_t)(b * NHEADS + h)) * SEQ + t) * DHEAD + dh0]) = o;
            }
        }
    } else {
        // unswapped layout: value (i,j,r) = C[token m0+wm+i*16+4g+r][col j*16+lm]
        #pragma unroll
        for (int j = 0; j < 4; ++j) {
            const int dh = j * 16 + lm;
            const float bv = bias[colbase + dh];
            #pragma unroll
            for (int i = 0; i < 4; ++i) {
                const int t0 = m0 + wm + i * 16 + 4 * g;
                const int b = t0 >> 10, t = t0 & 1023;
                ushort4 o;
                o.x = f2bf(acc[i][j][0] + bv);
                o.y = f2bf(acc[i][j][1] + bv);
                o.z = f2bf(acc[i][j][2] + bv);
                o.w = f2bf(acc[i][j][3] + bv);
                *reinterpret_cast<ushort4*>(
                    &vT[(((size_t)(b * NHEADS + h)) * DHEAD + dh) * SEQ + t]) = o;
            }
        }
    }
}

// ------------------------------------------------------- Proj GEMM (fp8 MX)
// A = msa fp8 [8192][1024], Bt = W_proj^T fp8. Epilogue: out = z + acc + bias.
__global__ __launch_bounds__(256, 2) void gemm_proj(
    const u8* __restrict__ A, const u8* __restrict__ Bt,
    const float* __restrict__ bias, const float* __restrict__ z,
    float* __restrict__ out)
{
    __shared__ u8 As[128 * 128];
    __shared__ u8 Bs[128 * 128];
    const int tid = threadIdx.x;
    const int wave = tid >> 6, lane = tid & 63;
    const int lm = lane & 15, g = lane >> 4;
    const int wm = (wave >> 1) * 64, wn = (wave & 1) * 64;
    const int m0 = blockIdx.y * 128, n0 = blockIdx.x * 128;
    const int srow = tid >> 3;
    const int sseg = tid & 7;
    const int sgcol = (sseg ^ (srow & 7)) * 16;
    const int xl = lm & 7;
    const int ca0 = ((2 * g) ^ xl) * 16;
    const int ca1 = ((2 * g + 1) ^ xl) * 16;
    f32x4 acc[4][4] = {};
    for (int k0 = 0; k0 < D_MODEL; k0 += 128) {
        #pragma unroll
        for (int c = 0; c < 4; ++c) {
            const int r = srow + c * 32;
            __builtin_amdgcn_global_load_lds(
                GPTR(&A[(size_t)(m0 + r) * D_MODEL + k0 + sgcol]),
                LPTR(&As[r * 128 + sseg * 16]), 16, 0, 0);
            __builtin_amdgcn_global_load_lds(
                GPTR(&Bt[(size_t)(n0 + r) * D_MODEL + k0 + sgcol]),
                LPTR(&Bs[r * 128 + sseg * 16]), 16, 0, 0);
        }
        __syncthreads();
        i32x8 af[4], bfr[4];
        #pragma unroll
        for (int i = 0; i < 4; ++i) {
            const uint4 alo = *reinterpret_cast<const uint4*>(&As[(wm + i*16 + lm) * 128 + ca0]);
            const uint4 ahi = *reinterpret_cast<const uint4*>(&As[(wm + i*16 + lm) * 128 + ca1]);
            af[i][0] = alo.x; af[i][1] = alo.y; af[i][2] = alo.z; af[i][3] = alo.w;
            af[i][4] = ahi.x; af[i][5] = ahi.y; af[i][6] = ahi.z; af[i][7] = ahi.w;
            const uint4 blo = *reinterpret_cast<const uint4*>(&Bs[(wn + i*16 + lm) * 128 + ca0]);
            const uint4 bhi = *reinterpret_cast<const uint4*>(&Bs[(wn + i*16 + lm) * 128 + ca1]);
            bfr[i][0] = blo.x; bfr[i][1] = blo.y; bfr[i][2] = blo.z; bfr[i][3] = blo.w;
            bfr[i][4] = bhi.x; bfr[i][5] = bhi.y; bfr[i][6] = bhi.z; bfr[i][7] = bhi.w;
        }
        #pragma unroll
        for (int i = 0; i < 4; ++i)
            #pragma unroll
            for (int j = 0; j < 4; ++j)
                acc[i][j] = MFMA_FP8_16x16x128(bfr[j], af[i], acc[i][j]);
        __syncthreads();
    }
    #pragma unroll
    for (int j = 0; j < 4; ++j) {
        const int col0 = n0 + wn + j * 16 + 4 * g;
        const float4 bv4 = *reinterpret_cast<const float4*>(&bias[col0]);
        #pragma unroll
        for (int i = 0; i < 4; ++i) {
            const int m = m0 + wm + i * 16 + lm;
            const size_t idx = (size_t)m * D_MODEL + col0;
            const float4 zv = *reinterpret_cast<const float4*>(&z[idx]);
            float4 ov;
            ov.x = zv.x + acc[i][j][0] + bv4.x;
            ov.y = zv.y + acc[i][j][1] + bv4.y;
            ov.z = zv.z + acc[i][j][2] + bv4.z;
            ov.w = zv.w + acc[i][j][3] + bv4.w;
            *reinterpret_cast<float4*>(&out[idx]) = ov;
        }
    }
}

// ------------------------------------------------------------ flash attention
// r9 structure: transposed-S, fixed-max softmax, 128 q-rows/block, x32 PV via
// tau-permuted V, Schraudolph bf16 exp2, MFMA-of-ones denominator.
// r11: msa output is fp8 e4m3 (feeds the fp8 proj GEMM).
#define KLD 68   // 64 + 4 pad halves (measured conflict-free r4/r6/r7)

__global__ __launch_bounds__(256, 4) void attn_kernel(
    const u16* __restrict__ Q, const u16* __restrict__ K,
    const u16* __restrict__ Vt, u8* __restrict__ msaf)
{
    __shared__ u16 Ks[64 * KLD];
    __shared__ u16 Vs[64 * KLD];
    const int tid = threadIdx.x, wave = tid >> 6, lane = tid & 63;
    const int lm = lane & 15, g = lane >> 4;
    const int bi = blockIdx.x;
    const int bh = bi & 127;            // same XCD for all q-tiles of a head
    const int q0 = (bi >> 7) * 128;
    const int b = bh >> 4, h = bh & 15;
    const size_t headBase = (size_t)bh * SEQ * DHEAD;
    const u16* Qh = Q + headBase;
    const u16* Kh = K + headBase;
    const u16* Vh = Vt + headBase;      // [64 dh][1024 t]

    const int srow = tid >> 3, sseg = tid & 7;
    const int aA = 16 * (sseg >> 2) + 4 * (sseg & 3);   // tau-permute chunk

    const uint4 onesu = {0x3F803F80u, 0x3F803F80u, 0x3F803F80u, 0x3F803F80u};
    const bf16x8 ONES = __builtin_bit_cast(bf16x8, onesu);

    bf16x8 qf[2][2];
    #pragma unroll
    for (int s = 0; s < 2; ++s) {
        const u16* qrow = Qh + (size_t)(q0 + s * 64 + wave * 16 + lm) * DHEAD;
        qf[s][0] = *reinterpret_cast<const bf16x8*>(qrow + g * 8);
        qf[s][1] = *reinterpret_cast<const bf16x8*>(qrow + 32 + g * 8);
    }

    f32x4 o[2][4] = {};
    f32x4 lacc[2] = {};

    for (int j0 = 0; j0 < SEQ; j0 += 64) {
        #pragma unroll
        for (int s2 = 0; s2 < 2; ++s2) {
            const int row = srow + 32 * s2;
            *reinterpret_cast<uint4*>(&Ks[row * KLD + sseg * 8]) =
                *reinterpret_cast<const uint4*>(&Kh[(size_t)(j0 + row) * DHEAD + sseg * 8]);
            const u16* vrow = Vh + (size_t)row * SEQ + j0;
            const uint2 va = *reinterpret_cast<const uint2*>(vrow + aA);
            const uint2 vb = *reinterpret_cast<const uint2*>(vrow + 32 + aA);
            uint4 wv; wv.x = va.x; wv.y = va.y; wv.z = vb.x; wv.w = vb.y;
            *reinterpret_cast<uint4*>(&Vs[row * KLD + sseg * 8]) = wv;
        }
        __syncthreads();

        bf16x8 kf0[4], kf1[4];
        #pragma unroll
        for (int ni = 0; ni < 4; ++ni) {
            kf0[ni] = *reinterpret_cast<const bf16x8*>(&Ks[(ni*16 + lm) * KLD + g * 8]);
            kf1[ni] = *reinterpret_cast<const bf16x8*>(&Ks[(ni*16 + lm) * KLD + 32 + g * 8]);
        }

        bf16x8 pfr[2][2];
        #pragma unroll
        for (int s = 0; s < 2; ++s) {
            f32x4 st[4];
            #pragma unroll
            for (int ni = 0; ni < 4; ++ni) {
                f32x4 zero = {};
                st[ni] = __builtin_amdgcn_mfma_f32_16x16x32_bf16(kf0[ni], qf[s][0], zero, 0, 0, 0);
                st[ni] = __builtin_amdgcn_mfma_f32_16x16x32_bf16(kf1[ni], qf[s][1], st[ni], 0, 0, 0);
            }
            int ip[4][4];
            #pragma unroll
            for (int ni = 0; ni < 4; ++ni)
                #pragma unroll
                for (int r = 0; r < 4; ++r)
                    ip[ni][r] = (int)__builtin_fmaf(st[ni][r], 128.0f, 16250.5f);
            #pragma unroll
            for (int c = 0; c < 2; ++c) {
                uint4 u;
                u.x = pklo(ip[c][1],   ip[c][0]);
                u.y = pklo(ip[c][3],   ip[c][2]);
                u.z = pklo(ip[c+2][1], ip[c+2][0]);
                u.w = pklo(ip[c+2][3], ip[c+2][2]);
                pfr[s][c] = __builtin_bit_cast(bf16x8, u);
            }
            lacc[s] = __builtin_amdgcn_mfma_f32_16x16x32_bf16(ONES, pfr[s][0], lacc[s], 0, 0, 0);
            lacc[s] = __builtin_amdgcn_mfma_f32_16x16x32_bf16(ONES, pfr[s][1], lacc[s], 0, 0, 0);
        }

        #pragma unroll
        for (int mt = 0; mt < 4; ++mt) {
            bf16x8 vf0 = *reinterpret_cast<const bf16x8*>(&Vs[(mt*16 + lm) * KLD + g * 8]);
            bf16x8 vf1 = *reinterpret_cast<const bf16x8*>(&Vs[(mt*16 + lm) * KLD + 32 + g * 8]);
            #pragma unroll
            for (int s = 0; s < 2; ++s) {
                o[s][mt] = __builtin_amdgcn_mfma_f32_16x16x32_bf16(vf0, pfr[s][0], o[s][mt], 0, 0, 0);
                o[s][mt] = __builtin_amdgcn_mfma_f32_16x16x32_bf16(vf1, pfr[s][1], o[s][mt], 0, 0, 0);
            }
        }
        __syncthreads();
    }

    #pragma unroll
    for (int s = 0; s < 2; ++s) {
        const float inv = 1.0f / lacc[s][0];
        const int t = q0 + s * 64 + wave * 16 + lm;
        const size_t base = ((size_t)b * SEQ + t) * D_MODEL + h * DHEAD;
        #pragma unroll
        for (int mt = 0; mt < 4; ++mt) {
            const int d0 = mt * 16 + 4 * g;
            int pk = CVT_PK_FP8(o[s][mt][0] * inv, o[s][mt][1] * inv, 0, false);
            pk = CVT_PK_FP8(o[s][mt][2] * inv, o[s][mt][3] * inv, pk, true);
            *reinterpret_cast<uint32_t*>(&msaf[base + d0]) = (uint32_t)pk;
        }
    }
}

// -------------------------------------------------------------------- launch
extern "C" void kernel_launch(void* const* d_in, const int* in_sizes, int n_in,
                              void* d_out, int out_size, void* d_ws, size_t ws_size,
                              hipStream_t stream) {
    const float* z      = (const float*)d_in[0];
    const float* ln_w   = (const float*)d_in[1];
    const float* ln_b   = (const float*)d_in[2];
    const float* W_qkv  = (const float*)d_in[3];
    const float* b_qkv  = (const float*)d_in[4];
    const float* W_proj = (const float*)d_in[5];
    const float* b_proj = (const float*)d_in[6];
    float* out = (float*)d_out;

    u8* ws = (u8*)d_ws;
    u8*  znf     = ws;                                      // fp8 [8192][1024]   8 MB
    u8*  wqkvTf  = znf + (size_t)MTOT * D_MODEL;            // fp8 [3072][1024]   3 MB
    u8*  wprojTf = wqkvTf + (size_t)3 * D_MODEL * D_MODEL;  // fp8 [1024][1024]   1 MB
    u8*  msaf    = wprojTf + (size_t)D_MODEL * D_MODEL;     // fp8 [8192][1024]   8 MB
    u16* q       = (u16*)(msaf + (size_t)MTOT * D_MODEL);   // bf16 [b,h,t,dh]   16 MB
    u16* k       = q + (size_t)MTOT * D_MODEL;              // bf16 [b,h,t,dh]   16 MB
    u16* vT      = k + (size_t)MTOT * D_MODEL;              // bf16 [b,h,dh,t]   16 MB

    ln_kernel<<<MTOT, 256, 0, stream>>>(z, ln_w, ln_b, (uint32_t*)znf);
    prep_weights<<<dim3(128, 32), 256, 0, stream>>>(W_qkv, W_proj, wqkvTf, wprojTf);
    gemm_qkv<<<dim3(3 * D_MODEL / 128, MTOT / 128), 256, 0, stream>>>(
        znf, wqkvTf, b_qkv, q, k, vT);
    attn_kernel<<<BATCH * NHEADS * (SEQ / 128), 256, 0, stream>>>(q, k, vT, msaf);
    gemm_proj<<<dim3(D_MODEL / 128, MTOT / 128), 256, 0, stream>>>(
        msaf, wprojTf, b_proj, z, out);
}

// Round 12
// 205.405 us; speedup vs baseline: 1.3752x; 1.0050x over previous
//
#include <hip/hip_runtime.h>
#include <stdint.h>

typedef unsigned short u16;
typedef uint8_t u8;
typedef __bf16 bf16x8 __attribute__((ext_vector_type(8)));
typedef float f32x4 __attribute__((ext_vector_type(4)));
typedef int i32x8 __attribute__((ext_vector_type(8)));

#define D_MODEL 1024
#define NHEADS  16
#define DHEAD   64
#define BATCH   8
#define SEQ     1024
#define MTOT    (BATCH*SEQ)          // 8192 rows

#define GPTR(p) ((const __attribute__((address_space(1))) void*)(p))
#define LPTR(p) ((__attribute__((address_space(3))) void*)(p))

// Device-only builtins (host pass just needs to parse — r2 lesson)
#if defined(__HIP_DEVICE_COMPILE__)
  #define MFMA_FP8_16x16x128(a, b, c) \
      __builtin_amdgcn_mfma_scale_f32_16x16x128_f8f6f4((a), (b), (c), 0, 0, 0, 127, 0, 127)
  #define CVT_PK_FP8(a, b, old, w) __builtin_amdgcn_cvt_pk_fp8_f32((a), (b), (old), (w))
#else
  #define MFMA_FP8_16x16x128(a, b, c) (c)
  #define CVT_PK_FP8(a, b, old, w) (0)
#endif

__device__ __forceinline__ u16 f2bf(float f) {
    union { float f; uint32_t u; } v; v.f = f;
    uint32_t u = v.u;
    u += 0x7fffu + ((u >> 16) & 1u);  // RNE
    return (u16)(u >> 16);
}

// pack low16 of two ints: result = [i1.low16 : i0.low16]
__device__ __forceinline__ uint32_t pklo(int i1, int i0) {
    return __builtin_amdgcn_perm((uint32_t)i1, (uint32_t)i0, 0x05040100u);
}

// --------------- merged prep: LayerNorm->fp8 (blocks 0..8191) and
//                 weight transpose->fp8 (blocks 8192..12287)
__global__ __launch_bounds__(256) void prep_inputs(
    const float* __restrict__ z, const float* __restrict__ w,
    const float* __restrict__ b, uint32_t* __restrict__ znf,
    const float* __restrict__ Wqkv, const float* __restrict__ Wproj,
    u8* __restrict__ outQkv, u8* __restrict__ outProj)
{
    __shared__ float red[8];
    __shared__ u8 tile[32][36];
    const int bid = blockIdx.x;
    const int t = threadIdx.x;
    if (bid < MTOT) {
        // ---- LayerNorm row
        const int row = bid;
        const float4 v = reinterpret_cast<const float4*>(z + (size_t)row * D_MODEL)[t];
        float s  = v.x + v.y + v.z + v.w;
        float s2 = v.x*v.x + v.y*v.y + v.z*v.z + v.w*v.w;
        #pragma unroll
        for (int off = 32; off; off >>= 1) {
            s  += __shfl_down(s,  off, 64);
            s2 += __shfl_down(s2, off, 64);
        }
        const int wave = t >> 6, lane = t & 63;
        if (lane == 0) { red[wave] = s; red[wave + 4] = s2; }
        __syncthreads();
        if (t == 0) {
            float ts  = red[0] + red[1] + red[2] + red[3];
            float ts2 = red[4] + red[5] + red[6] + red[7];
            float mu  = ts * (1.0f / D_MODEL);
            float var = ts2 * (1.0f / D_MODEL) - mu * mu;
            red[0] = mu; red[1] = rsqrtf(var + 1e-5f);
        }
        __syncthreads();
        const float mu = red[0], rstd = red[1];
        const float4 wv = reinterpret_cast<const float4*>(w)[t];
        const float4 bv = reinterpret_cast<const float4*>(b)[t];
        const float x0 = (v.x - mu) * rstd * wv.x + bv.x;
        const float x1 = (v.y - mu) * rstd * wv.y + bv.y;
        const float x2 = (v.z - mu) * rstd * wv.z + bv.z;
        const float x3 = (v.w - mu) * rstd * wv.w + bv.w;
        int pk = CVT_PK_FP8(x0, x1, 0, false);
        pk = CVT_PK_FP8(x2, x3, pk, true);
        znf[(size_t)row * (D_MODEL / 4) + t] = (uint32_t)pk;
    } else {
        // ---- weight transpose + fp8 cast (32x32 tile)
        const int bx = bid - MTOT;            // 0..4095
        const int cx = bx & 127;              // 128 column-tiles
        const int r0 = (bx >> 7) * 32;        // 32 row-tiles
        const float* in; u8* out; int C;
        if (cx < 96) { in = Wqkv;  out = outQkv;  C = 3072; }
        else         { in = Wproj; out = outProj; C = 1024; }
        const int c0 = (cx < 96 ? cx : cx - 96) * 32;
        const int tx = t & 31, ty = t >> 5;   // 32x8
        #pragma unroll
        for (int i = 0; i < 4; ++i) {
            const float f = in[(size_t)(r0 + ty + i*8) * C + c0 + tx];
            tile[ty + i*8][tx] = (u8)(CVT_PK_FP8(f, 0.f, 0, false) & 0xFF);
        }
        __syncthreads();
        #pragma unroll
        for (int i = 0; i < 4; ++i)
            out[(size_t)(c0 + ty + i*8) * D_MODEL + r0 + tx] = tile[tx][ty + i*8];
    }
}

#define QSCALE 0.180336880f   // 0.125 * log2(e): folded into q for exp2 softmax

// ---------------------------------------------------------- fp8 GEMM mainloop
// 128x128 tile, K-tile=128B, 4 waves; XOR swizzle; global_load_lds width-16.
// MFMA_STMT uses af[i] (A-rows) and bfr[j] (B-rows) -> acc[i][j].
#define FP8_MAINLOOP(A_, Bt_, MFMA_STMT)                                        \
    __shared__ u8 As[128 * 128];                                                \
    __shared__ u8 Bs[128 * 128];                                                \
    const int tid = threadIdx.x;                                                \
    const int wave = tid >> 6, lane = tid & 63;                                 \
    const int lm = lane & 15, g = lane >> 4;                                    \
    const int wm = (wave >> 1) * 64, wn = (wave & 1) * 64;                      \
    const int m0 = blockIdx.y * 128, n0 = blockIdx.x * 128;                     \
    const int srow = tid >> 3;                                                  \
    const int sseg = tid & 7;                                                   \
    const int sgcol = (sseg ^ (srow & 7)) * 16;                                 \
    const int xl = lm & 7;                                                      \
    const int ca0 = ((2 * g) ^ xl) * 16;                                        \
    const int ca1 = ((2 * g + 1) ^ xl) * 16;                                    \
    f32x4 acc[4][4] = {};                                                       \
    for (int k0 = 0; k0 < D_MODEL; k0 += 128) {                                 \
        _Pragma("unroll")                                                       \
        for (int c = 0; c < 4; ++c) {                                           \
            const int r = srow + c * 32;                                        \
            __builtin_amdgcn_global_load_lds(                                   \
                GPTR(&A_[(size_t)(m0 + r) * D_MODEL + k0 + sgcol]),             \
                LPTR(&As[r * 128 + sseg * 16]), 16, 0, 0);                      \
            __builtin_amdgcn_global_load_lds(                                   \
                GPTR(&Bt_[(size_t)(n0 + r) * D_MODEL + k0 + sgcol]),            \
                LPTR(&Bs[r * 128 + sseg * 16]), 16, 0, 0);                      \
        }                                                                       \
        __syncthreads();                                                        \
        i32x8 af[4], bfr[4];                                                    \
        _Pragma("unroll")                                                       \
        for (int i = 0; i < 4; ++i) {                                           \
            const uint4 alo = *reinterpret_cast<const uint4*>(&As[(wm + i*16 + lm) * 128 + ca0]); \
            const uint4 ahi = *reinterpret_cast<const uint4*>(&As[(wm + i*16 + lm) * 128 + ca1]); \
            af[i][0] = alo.x; af[i][1] = alo.y; af[i][2] = alo.z; af[i][3] = alo.w; \
            af[i][4] = ahi.x; af[i][5] = ahi.y; af[i][6] = ahi.z; af[i][7] = ahi.w; \
            const uint4 blo = *reinterpret_cast<const uint4*>(&Bs[(wn + i*16 + lm) * 128 + ca0]); \
            const uint4 bhi = *reinterpret_cast<const uint4*>(&Bs[(wn + i*16 + lm) * 128 + ca1]); \
            bfr[i][0] = blo.x; bfr[i][1] = blo.y; bfr[i][2] = blo.z; bfr[i][3] = blo.w; \
            bfr[i][4] = bhi.x; bfr[i][5] = bhi.y; bfr[i][6] = bhi.z; bfr[i][7] = bhi.w; \
        }                                                                       \
        _Pragma("unroll")                                                       \
        for (int i = 0; i < 4; ++i)                                             \
            _Pragma("unroll")                                                   \
            for (int j = 0; j < 4; ++j)                                         \
                MFMA_STMT;                                                      \
        __syncthreads();                                                        \
    }

// ------------------------------------------------- Q/K GEMM (swapped operands)
// acc[i][j][r] = C[m...+lm][col ...+4g+r] -> lane owns 4 consecutive dh.
__global__ __launch_bounds__(256, 2) void gemm_qk(
    const u8* __restrict__ A, const u8* __restrict__ Bt,
    const float* __restrict__ bias,
    u16* __restrict__ q, u16* __restrict__ k)
{
    FP8_MAINLOOP(A, Bt, acc[i][j] = MFMA_FP8_16x16x128(bfr[j], af[i], acc[i][j]))
    const int colbase = n0 + wn;
    const int sel = colbase >> 10;          // 0=q 1=k (grid x < 16)
    const int h = (colbase & 1023) >> 6;
    u16* dst = (sel == 0) ? q : k;
    const float scl = (sel == 0) ? QSCALE : 1.0f;
    #pragma unroll
    for (int j = 0; j < 4; ++j) {
        const int dh0 = j * 16 + 4 * g;
        const float4 bv4 = *reinterpret_cast<const float4*>(&bias[colbase + dh0]);
        #pragma unroll
        for (int i = 0; i < 4; ++i) {
            const int m = m0 + wm + i * 16 + lm;
            const int b = m >> 10, t = m & 1023;
            ushort4 o;
            o.x = f2bf((acc[i][j][0] + bv4.x) * scl);
            o.y = f2bf((acc[i][j][1] + bv4.y) * scl);
            o.z = f2bf((acc[i][j][2] + bv4.z) * scl);
            o.w = f2bf((acc[i][j][3] + bv4.w) * scl);
            *reinterpret_cast<ushort4*>(
                &dst[(((size_t)(b * NHEADS + h)) * SEQ + t) * DHEAD + dh0]) = o;
        }
    }
}

// ------------------------------------------------- V GEMM (unswapped operands)
// acc[i][j][r] = C[token m...+4g+r][col j*16+lm] -> writes vT[b,h,dh,t] direct.
__global__ __launch_bounds__(256, 2) void gemm_v(
    const u8* __restrict__ A, const u8* __restrict__ Btv,
    const float* __restrict__ biasv, u16* __restrict__ vT)
{
    FP8_MAINLOOP(A, Btv, acc[i][j] = MFMA_FP8_16x16x128(af[i], bfr[j], acc[i][j]))
    const int colbase = n0 + wn;            // 0..1023 within v
    const int h = colbase >> 6;
    #pragma unroll
    for (int j = 0; j < 4; ++j) {
        const int dh = ((colbase & 63) + j * 16) + lm;   // j*16+lm within head
        const float bv = biasv[colbase + j * 16 + lm];
        #pragma unroll
        for (int i = 0; i < 4; ++i) {
            const int t0 = m0 + wm + i * 16 + 4 * g;
            const int b = t0 >> 10, t = t0 & 1023;
            ushort4 o;
            o.x = f2bf(acc[i][j][0] + bv);
            o.y = f2bf(acc[i][j][1] + bv);
            o.z = f2bf(acc[i][j][2] + bv);
            o.w = f2bf(acc[i][j][3] + bv);
            *reinterpret_cast<ushort4*>(
                &vT[(((size_t)(b * NHEADS + h)) * DHEAD + dh) * SEQ + t]) = o;
        }
    }
}

// ------------------------------------------------------- Proj GEMM (fp8 MX)
__global__ __launch_bounds__(256, 2) void gemm_proj(
    const u8* __restrict__ A, const u8* __restrict__ Bt,
    const float* __restrict__ bias, const float* __restrict__ z,
    float* __restrict__ out)
{
    FP8_MAINLOOP(A, Bt, acc[i][j] = MFMA_FP8_16x16x128(bfr[j], af[i], acc[i][j]))
    #pragma unroll
    for (int j = 0; j < 4; ++j) {
        const int col0 = n0 + wn + j * 16 + 4 * g;
        const float4 bv4 = *reinterpret_cast<const float4*>(&bias[col0]);
        #pragma unroll
        for (int i = 0; i < 4; ++i) {
            const int m = m0 + wm + i * 16 + lm;
            const size_t idx = (size_t)m * D_MODEL + col0;
            const float4 zv = *reinterpret_cast<const float4*>(&z[idx]);
            float4 ov;
            ov.x = zv.x + acc[i][j][0] + bv4.x;
            ov.y = zv.y + acc[i][j][1] + bv4.y;
            ov.z = zv.z + acc[i][j][2] + bv4.z;
            ov.w = zv.w + acc[i][j][3] + bv4.w;
            *reinterpret_cast<float4*>(&out[idx]) = ov;
        }
    }
}

// ------------------------------------------------------------ flash attention
// r9 structure: transposed-S, fixed-max softmax, 128 q-rows/block, x32 PV via
// tau-permuted V, Schraudolph bf16 exp2, MFMA-of-ones denominator; fp8 msa out.
#define KLD 68   // 64 + 4 pad halves (measured conflict-free r4/r6/r7)

__global__ __launch_bounds__(256, 4) void attn_kernel(
    const u16* __restrict__ Q, const u16* __restrict__ K,
    const u16* __restrict__ Vt, u8* __restrict__ msaf)
{
    __shared__ u16 Ks[64 * KLD];
    __shared__ u16 Vs[64 * KLD];
    const int tid = threadIdx.x, wave = tid >> 6, lane = tid & 63;
    const int lm = lane & 15, g = lane >> 4;
    const int bi = blockIdx.x;
    const int bh = bi & 127;            // same XCD for all q-tiles of a head
    const int q0 = (bi >> 7) * 128;
    const int b = bh >> 4, h = bh & 15;
    const size_t headBase = (size_t)bh * SEQ * DHEAD;
    const u16* Qh = Q + headBase;
    const u16* Kh = K + headBase;
    const u16* Vh = Vt + headBase;      // [64 dh][1024 t]

    const int srow = tid >> 3, sseg = tid & 7;
    const int aA = 16 * (sseg >> 2) + 4 * (sseg & 3);   // tau-permute chunk

    const uint4 onesu = {0x3F803F80u, 0x3F803F80u, 0x3F803F80u, 0x3F803F80u};
    const bf16x8 ONES = __builtin_bit_cast(bf16x8, onesu);

    bf16x8 qf[2][2];
    #pragma unroll
    for (int s = 0; s < 2; ++s) {
        const u16* qrow = Qh + (size_t)(q0 + s * 64 + wave * 16 + lm) * DHEAD;
        qf[s][0] = *reinterpret_cast<const bf16x8*>(qrow + g * 8);
        qf[s][1] = *reinterpret_cast<const bf16x8*>(qrow + 32 + g * 8);
    }

    f32x4 o[2][4] = {};
    f32x4 lacc[2] = {};

    for (int j0 = 0; j0 < SEQ; j0 += 64) {
        #pragma unroll
        for (int s2 = 0; s2 < 2; ++s2) {
            const int row = srow + 32 * s2;
            *reinterpret_cast<uint4*>(&Ks[row * KLD + sseg * 8]) =
                *reinterpret_cast<const uint4*>(&Kh[(size_t)(j0 + row) * DHEAD + sseg * 8]);
            const u16* vrow = Vh + (size_t)row * SEQ + j0;
            const uint2 va = *reinterpret_cast<const uint2*>(vrow + aA);
            const uint2 vb = *reinterpret_cast<const uint2*>(vrow + 32 + aA);
            uint4 wv; wv.x = va.x; wv.y = va.y; wv.z = vb.x; wv.w = vb.y;
            *reinterpret_cast<uint4*>(&Vs[row * KLD + sseg * 8]) = wv;
        }
        __syncthreads();

        bf16x8 kf0[4], kf1[4];
        #pragma unroll
        for (int ni = 0; ni < 4; ++ni) {
            kf0[ni] = *reinterpret_cast<const bf16x8*>(&Ks[(ni*16 + lm) * KLD + g * 8]);
            kf1[ni] = *reinterpret_cast<const bf16x8*>(&Ks[(ni*16 + lm) * KLD + 32 + g * 8]);
        }

        bf16x8 pfr[2][2];
        #pragma unroll
        for (int s = 0; s < 2; ++s) {
            f32x4 st[4];
            #pragma unroll
            for (int ni = 0; ni < 4; ++ni) {
                f32x4 zero = {};
                st[ni] = __builtin_amdgcn_mfma_f32_16x16x32_bf16(kf0[ni], qf[s][0], zero, 0, 0, 0);
                st[ni] = __builtin_amdgcn_mfma_f32_16x16x32_bf16(kf1[ni], qf[s][1], st[ni], 0, 0, 0);
            }
            int ip[4][4];
            #pragma unroll
            for (int ni = 0; ni < 4; ++ni)
                #pragma unroll
                for (int r = 0; r < 4; ++r)
                    ip[ni][r] = (int)__builtin_fmaf(st[ni][r], 128.0f, 16250.5f);
            #pragma unroll
            for (int c = 0; c < 2; ++c) {
                uint4 u;
                u.x = pklo(ip[c][1],   ip[c][0]);
                u.y = pklo(ip[c][3],   ip[c][2]);
                u.z = pklo(ip[c+2][1], ip[c+2][0]);
                u.w = pklo(ip[c+2][3], ip[c+2][2]);
                pfr[s][c] = __builtin_bit_cast(bf16x8, u);
            }
            lacc[s] = __builtin_amdgcn_mfma_f32_16x16x32_bf16(ONES, pfr[s][0], lacc[s], 0, 0, 0);
            lacc[s] = __builtin_amdgcn_mfma_f32_16x16x32_bf16(ONES, pfr[s][1], lacc[s], 0, 0, 0);
        }

        #pragma unroll
        for (int mt = 0; mt < 4; ++mt) {
            bf16x8 vf0 = *reinterpret_cast<const bf16x8*>(&Vs[(mt*16 + lm) * KLD + g * 8]);
            bf16x8 vf1 = *reinterpret_cast<const bf16x8*>(&Vs[(mt*16 + lm) * KLD + 32 + g * 8]);
            #pragma unroll
            for (int s = 0; s < 2; ++s) {
                o[s][mt] = __builtin_amdgcn_mfma_f32_16x16x32_bf16(vf0, pfr[s][0], o[s][mt], 0, 0, 0);
                o[s][mt] = __builtin_amdgcn_mfma_f32_16x16x32_bf16(vf1, pfr[s][1], o[s][mt], 0, 0, 0);
            }
        }
        __syncthreads();
    }

    #pragma unroll
    for (int s = 0; s < 2; ++s) {
        const float inv = 1.0f / lacc[s][0];
        const int t = q0 + s * 64 + wave * 16 + lm;
        const size_t base = ((size_t)b * SEQ + t) * D_MODEL + h * DHEAD;
        #pragma unroll
        for (int mt = 0; mt < 4; ++mt) {
            const int d0 = mt * 16 + 4 * g;
            int pk = CVT_PK_FP8(o[s][mt][0] * inv, o[s][mt][1] * inv, 0, false);
            pk = CVT_PK_FP8(o[s][mt][2] * inv, o[s][mt][3] * inv, pk, true);
            *reinterpret_cast<uint32_t*>(&msaf[base + d0]) = (uint32_t)pk;
        }
    }
}

// -------------------------------------------------------------------- launch
extern "C" void kernel_launch(void* const* d_in, const int* in_sizes, int n_in,
                              void* d_out, int out_size, void* d_ws, size_t ws_size,
                              hipStream_t stream) {
    const float* z      = (const float*)d_in[0];
    const float* ln_w   = (const float*)d_in[1];
    const float* ln_b   = (const float*)d_in[2];
    const float* W_qkv  = (const float*)d_in[3];
    const float* b_qkv  = (const float*)d_in[4];
    const float* W_proj = (const float*)d_in[5];
    const float* b_proj = (const float*)d_in[6];
    float* out = (float*)d_out;

    u8* ws = (u8*)d_ws;
    u8*  znf     = ws;                                      // fp8 [8192][1024]   8 MB
    u8*  wqkvTf  = znf + (size_t)MTOT * D_MODEL;            // fp8 [3072][1024]   3 MB
    u8*  wprojTf = wqkvTf + (size_t)3 * D_MODEL * D_MODEL;  // fp8 [1024][1024]   1 MB
    u8*  msaf    = wprojTf + (size_t)D_MODEL * D_MODEL;     // fp8 [8192][1024]   8 MB
    u16* q       = (u16*)(msaf + (size_t)MTOT * D_MODEL);   // bf16 [b,h,t,dh]   16 MB
    u16* k       = q + (size_t)MTOT * D_MODEL;              // bf16 [b,h,t,dh]   16 MB
    u16* vT      = k + (size_t)MTOT * D_MODEL;              // bf16 [b,h,dh,t]   16 MB

    prep_inputs<<<MTOT + 4096, 256, 0, stream>>>(
        z, ln_w, ln_b, (uint32_t*)znf, W_qkv, W_proj, wqkvTf, wprojTf);
    gemm_qk<<<dim3(16, MTOT / 128), 256, 0, stream>>>(znf, wqkvTf, b_qkv, q, k);
    gemm_v<<<dim3(8, MTOT / 128), 256, 0, stream>>>(
        znf, wqkvTf + (size_t)2048 * D_MODEL, b_qkv + 2048, vT);
    attn_kernel<<<BATCH * NHEADS * (SEQ / 128), 256, 0, stream>>>(q, k, vT, msaf);
    gemm_proj<<<dim3(D_MODEL / 128, MTOT / 128), 256, 0, stream>>>(
        msaf, wprojTf, b_proj, z, out);
}